// Round 6
// baseline (596.099 us; speedup 1.0000x reference)
//
#include <hip/hip_runtime.h>
#include <hip/hip_bf16.h>
#include <math.h>

// ---------------------------------------------------------------------------
// EncoderBlock on MI355X (gfx950). B=8, S=1024, D=1024, H=16, DH=64, F=4096.
// Round 13: (1) attn softmax exp2-folding -- log2e folded into the fmaf
// constants so each probability is a single v_exp_f32 (deletes 512 v_mul per
// thread; attn is VALU-bound at 38% after the XCD remap). (2) gemm256
// epilogue: ping-pong wave scratch between dead As/Bs (drops the per-pass
// lgkm drain; store latency overlaps next pass's ds_writes) + 16 B/lane
// bf16 stores (2x dwordx4 iters instead of 4x dwordx2).
// Round-12 attn XCD remap and round-11 split-K retained unchanged.
// ---------------------------------------------------------------------------

typedef __hip_bfloat16 bf16;
typedef short bf16x8 __attribute__((ext_vector_type(8)));   // MFMA A/B frag (8 bf16)
typedef short bf16x4 __attribute__((ext_vector_type(4)));   // half-frag (8 B)
typedef float f32x4 __attribute__((ext_vector_type(4)));    // MFMA C/D frag

typedef unsigned int __attribute__((address_space(1))) as1_uint;
typedef unsigned int __attribute__((address_space(3))) as3_uint;

#define MFMA16(a, b, c) __builtin_amdgcn_mfma_f32_16x16x32_bf16((a), (b), (c), 0, 0, 0)
#define FLAG_RELU 1
#define FLAG_QKV 4
#define FLAG_OUTF32 8
#define FLAG_SPLITK 16
#define KSTRIDE 68    // K-tile row stride (dh 64 + 4 pad)
#define VSTRIDE 132   // V-tile row stride (s 128 + 4 pad)
// exp2-folded softmax constants (LOG2E = 1.44269504)
#define SM_SCALE2 0.18033688f      // 0.125 * log2e
#define SM_MASK2 -1.44269504e9f    // -1e9 * log2e
#define SM_SHIFT2 -28.8539008f     // -20 * log2e

// compiler-fenced raw barrier (no implicit vmcnt(0) drain like __syncthreads)
#define BAR() do { asm volatile("" ::: "memory"); \
    __builtin_amdgcn_s_barrier(); \
    asm volatile("" ::: "memory"); } while (0)
#define WAIT_LGKM0() do { asm volatile("s_waitcnt lgkmcnt(0)" ::: "memory"); \
    __builtin_amdgcn_sched_barrier(0); } while (0)
#define WAIT_VM4() do { asm volatile("s_waitcnt vmcnt(4)" ::: "memory"); \
    __builtin_amdgcn_sched_barrier(0); } while (0)
#define WAIT_VM0() do { asm volatile("s_waitcnt vmcnt(0)" ::: "memory"); \
    __builtin_amdgcn_sched_barrier(0); } while (0)

__device__ __forceinline__ float b2f(bf16 v) { return __bfloat162float(v); }
__device__ __forceinline__ bf16 f2b(float v) { return __float2bfloat16(v); }
__device__ __forceinline__ short f2bs(float v) {
    union { bf16 h; short s; } u;
    u.h = f2b(v);
    return u.s;
}
__device__ __forceinline__ float us2f(unsigned short u) {
    return __uint_as_float(((unsigned int)u) << 16);
}

__device__ __forceinline__ void async_copy16(void* lds, const void* gp) {
    __builtin_amdgcn_global_load_lds((const as1_uint*)gp, (as3_uint*)lds, 16, 0, 0);
}

// ---------------------------------------------------------------------------
// Input dtype detector (flag=1 -> inputs are float32).
// ---------------------------------------------------------------------------
__global__ void detect_k(const unsigned short* __restrict__ xs, int* flag) {
    __shared__ int vote;
    if (threadIdx.x == 0) vote = 0;
    __syncthreads();
    int bad = 0;
    for (int i = threadIdx.x; i < 16384; i += 256) {
        int e = (xs[i] >> 7) & 0xFF;
        if (e >= 0x84) bad = 1;
    }
    if (bad) atomicOr(&vote, 1);
    __syncthreads();
    if (threadIdx.x == 0) *flag = vote;
}

// ---------------------------------------------------------------------------
// Convert large tensor to bf16.
// ---------------------------------------------------------------------------
__global__ __launch_bounds__(256) void cvt_k(const void* __restrict__ in,
                                             bf16* __restrict__ out, int n,
                                             const int* __restrict__ flag) {
    const int f = *flag;
    const int base = (blockIdx.x * 256 + threadIdx.x) * 4;
    if (f) {
        const float* p = (const float*)in;
#pragma unroll
        for (int j = 0; j < 4; j++) {
            int i = base + j;
            if (i < n) out[i] = f2b(p[i]);
        }
    } else {
        const bf16* p = (const bf16*)in;
#pragma unroll
        for (int j = 0; j < 4; j++) {
            int i = base + j;
            if (i < n) out[i] = p[i];
        }
    }
}

// ---------------------------------------------------------------------------
// Batched conversion of the 11 small tensors (one block per tensor).
// ---------------------------------------------------------------------------
struct CvtBatch {
    const void* src[11];
    bf16* dst[11];
    int n[11];
};
__global__ __launch_bounds__(256) void cvt_small_k(CvtBatch cb,
                                                   const int* __restrict__ flag) {
    const int f = *flag;
    const int seg = blockIdx.x;
    const int n = cb.n[seg];
    const void* in = cb.src[seg];
    bf16* out = cb.dst[seg];
    if (f) {
        const float* p = (const float*)in;
        for (int i = threadIdx.x; i < n; i += 256) out[i] = f2b(p[i]);
    } else {
        const bf16* p = (const bf16*)in;
        for (int i = threadIdx.x; i < n; i += 256) out[i] = p[i];
    }
}

// ---------------------------------------------------------------------------
// Transpose: out[z][C][R] = in[z][R][C]. flag-aware read (nullptr = bf16).
// ---------------------------------------------------------------------------
__global__ __launch_bounds__(256) void transpose_k(const void* __restrict__ in,
                                                   bf16* __restrict__ out,
                                                   int R, int C,
                                                   const int* __restrict__ flag) {
    __shared__ bf16 tile[64][65];
    const int f = flag ? *flag : 0;
    const int tid = threadIdx.x;
    const size_t zoff = (size_t)blockIdx.z * R * C;
    const int tr = blockIdx.y * 64, tc = blockIdx.x * 64;
#pragma unroll
    for (int i = 0; i < 16; i++) {
        int idx = i * 256 + tid;
        int r = idx >> 6, c = idx & 63;
        size_t g = zoff + (size_t)(tr + r) * C + tc + c;
        tile[r][c] = f ? f2b(((const float*)in)[g]) : ((const bf16*)in)[g];
    }
    __syncthreads();
#pragma unroll
    for (int i = 0; i < 16; i++) {
        int idx = i * 256 + tid;
        int r = idx >> 6, c = idx & 63;
        out[zoff + (size_t)(tc + r) * R + tr + c] = tile[c][r];
    }
}

// ---------------------------------------------------------------------------
// 256x256 8-phase GEMM: C[M,N](ldc) = A[M,K](lda) @ Bt[N,K](ldb)^T + bias.
// 512 threads = 8 waves (2M x 4N), per-wave 128x64 output (acc[8][4]), BK=64.
// T2 swizzle + T3/T4 counted-vmcnt pipeline + T5 setprio (see round 8/9).
// FLAG_SPLITK: grid = 2*(M/256)*(N/256); kpart = swz&1 selects K-half;
// fp32 partial to Cv (kpart0, +bias) / Cv2 (kpart1, no bias). No RELU.
// Epilogue: wave-private scratch ping-pongs between dead As/Bs (no per-pass
// lgkm drain); bf16 path stores 16 B/lane. Requires M%256==0, N%256==0,
// K%64==0 (K%128==0 if split), nwg%8==0.
// ---------------------------------------------------------------------------
__global__ __launch_bounds__(512, 2) void gemm256(const bf16* __restrict__ A, int lda,
                                                  const bf16* __restrict__ Bt, int ldb,
                                                  const bf16* __restrict__ bias,
                                                  void* __restrict__ Cv, int ldc,
                                                  int M, int N, int K, int flags,
                                                  const int* __restrict__ dtf,
                                                  void* __restrict__ Cv2) {
    __shared__ __align__(16) bf16 As[2][256 * 64];   // 64 KiB
    __shared__ __align__(16) bf16 Bs[2][256 * 64];   // 64 KiB
    const int tid = threadIdx.x;
    const int wave = tid >> 6, lane = tid & 63;
    const int qd = lane >> 4, l15 = lane & 15;
    const int wm = wave >> 2, wn = wave & 3;         // 2 x 4 wave grid

    // XCD-aware block swizzle (nwg is a multiple of 8 for all our shapes)
    const int NB = N >> 8;
    const int cpx = gridDim.x >> 3;
    const int swz = ((int)blockIdx.x & 7) * cpx + ((int)blockIdx.x >> 3);
    const int splitk = flags & FLAG_SPLITK;
    const int kpart = splitk ? (swz & 1) : 0;
    const int tileIdx = splitk ? (swz >> 1) : swz;
    const int bn = tileIdx % NB, bm = tileIdx / NB;
    const int Keff = splitk ? (K >> 1) : K;
    const int koff = kpart ? Keff : 0;

    // ---- staging: pre-swizzled global source, linear LDS dest ----
    const int srow = tid >> 3;                        // 0..63 (row in sweep)
    const int schunk = (tid & 7) ^ (srow & 7);        // XOR-swizzled k-chunk
    const bf16* gA = A + (size_t)(bm * 256 + srow) * lda + koff + schunk * 8;
    const bf16* gB = Bt + (size_t)(bn * 256 + srow) * ldb + koff + schunk * 8;
    char* lA = (char*)As + wave * 1024;
    char* lB = (char*)Bs + wave * 1024;

    auto stA = [&](int d, int h, int tt) {
        const bf16* g = gA + (size_t)(h * 128) * lda + tt * 64;
        char* l = lA + d * 32768 + h * 16384;
        async_copy16(l, g);
        async_copy16(l + 8192, g + (size_t)64 * lda);
    };
    auto stB = [&](int d, int h, int tt) {
        const bf16* g = gB + (size_t)(h * 128) * ldb + tt * 64;
        char* l = lB + d * 32768 + h * 16384;
        async_copy16(l, g);
        async_copy16(l + 8192, g + (size_t)64 * ldb);
    };

    // ---- swizzled ds_read offsets (bytes). row&7 == l15&7 for all frags ----
    const int sx = l15 & 7;
    const char* pA = (const char*)As + (wm * 128 + l15) * 128;
    const char* pB = (const char*)Bs + (wn * 64 + l15) * 128;
    const int c0 = ((0 + qd) ^ sx) * 16;   // kk=0: global chunk qd
    const int c1 = ((4 + qd) ^ sx) * 16;   // kk=1: global chunk 4+qd

    f32x4 acc[8][4] = {};
    bf16x8 af[4][2], bfr[4][2];
    const int nt = Keff >> 6;

    // ---- prologue: tile 0 fully + B0/A0 of tile 1 in flight ----
    stA(0, 0, 0); stA(0, 1, 0); stB(0, 0, 0); stB(0, 1, 0);
    if (nt > 1) {
        stB(1, 0, 1); stA(1, 0, 1);
        WAIT_VM4();
    } else {
        WAIT_VM0();
    }
    BAR();

#pragma unroll 2
    for (int t = 0; t < nt; ++t) {
        const int d = t & 1, dn = d ^ 1;
        const int db = d * 32768;
        // ---------- phase 1: quadrant (m0-3, n0-1); 12 ds_reads ----------
#pragma unroll
        for (int m = 0; m < 4; ++m) {
            af[m][0] = *(const bf16x8*)(pA + db + m * 2048 + c0);
            af[m][1] = *(const bf16x8*)(pA + db + m * 2048 + c1);
        }
#pragma unroll
        for (int n = 0; n < 2; ++n) {
            bfr[n][0] = *(const bf16x8*)(pB + db + n * 2048 + c0);
            bfr[n][1] = *(const bf16x8*)(pB + db + n * 2048 + c1);
        }
        if (t + 1 < nt) stB(dn, 1, t + 1);
        BAR();
        WAIT_LGKM0();
        __builtin_amdgcn_s_setprio(1);
#pragma unroll
        for (int kk = 0; kk < 2; ++kk)
#pragma unroll
            for (int m = 0; m < 4; ++m)
#pragma unroll
                for (int n = 0; n < 2; ++n)
                    acc[m][n] = MFMA16(af[m][kk], bfr[n][kk], acc[m][n]);
        __builtin_amdgcn_s_setprio(0);
        BAR();
        // ---------- phase 2: quadrant (m0-3, n2-3); 4 ds_reads ----------
#pragma unroll
        for (int n = 0; n < 2; ++n) {
            bfr[2 + n][0] = *(const bf16x8*)(pB + db + (2 + n) * 2048 + c0);
            bfr[2 + n][1] = *(const bf16x8*)(pB + db + (2 + n) * 2048 + c1);
        }
        if (t + 1 < nt) stA(dn, 1, t + 1);
        BAR();
        WAIT_LGKM0();
        __builtin_amdgcn_s_setprio(1);
#pragma unroll
        for (int kk = 0; kk < 2; ++kk)
#pragma unroll
            for (int m = 0; m < 4; ++m)
#pragma unroll
                for (int n = 0; n < 2; ++n)
                    acc[m][2 + n] = MFMA16(af[m][kk], bfr[2 + n][kk], acc[m][2 + n]);
        __builtin_amdgcn_s_setprio(0);
        BAR();
        // ---------- phase 3: quadrant (m4-7, n0-1); 8 ds_reads ----------
#pragma unroll
        for (int m = 0; m < 4; ++m) {
            af[m][0] = *(const bf16x8*)(pA + db + (4 + m) * 2048 + c0);
            af[m][1] = *(const bf16x8*)(pA + db + (4 + m) * 2048 + c1);
        }
        if (t + 2 < nt) stB(d, 0, t + 2);
        BAR();
        WAIT_LGKM0();
        __builtin_amdgcn_s_setprio(1);
#pragma unroll
        for (int kk = 0; kk < 2; ++kk)
#pragma unroll
            for (int m = 0; m < 4; ++m)
#pragma unroll
                for (int n = 0; n < 2; ++n)
                    acc[4 + m][n] = MFMA16(af[m][kk], bfr[n][kk], acc[4 + m][n]);
        __builtin_amdgcn_s_setprio(0);
        BAR();
        // ---------- phase 4: quadrant (m4-7, n2-3); no ds_reads ----------
        if (t + 2 < nt) stA(d, 0, t + 2);
        BAR();
        __builtin_amdgcn_s_setprio(1);
#pragma unroll
        for (int kk = 0; kk < 2; ++kk)
#pragma unroll
            for (int m = 0; m < 4; ++m)
#pragma unroll
                for (int n = 0; n < 2; ++n)
                    acc[4 + m][2 + n] = MFMA16(af[m][kk], bfr[2 + n][kk], acc[4 + m][2 + n]);
        __builtin_amdgcn_s_setprio(0);
        // counted wait: everything tile t+1 needs has landed; only the
        // newest 4 loads (B0/A0 of tile t+2) may stay in flight.
        if (t + 2 < nt) {
            WAIT_VM4();
        } else {
            WAIT_VM0();
        }
        BAR();
    }

    // ---- epilogue: ping-pong wave-private LDS bounce -> wide stores ----
    // Scratch alternates between dead As and Bs (8 waves x 4352 B each);
    // no barriers (wave-private), and writes of pass p+1 overlap the
    // outstanding reads/stores of pass p (different buffer).
    const int of32 = (flags & FLAG_OUTF32) ? *dtf : 0;
    bf16* C = (bf16*)Cv;
    float* Cf = (float*)(kpart ? Cv2 : Cv);
    float* ep0 = (float*)((char*)As + wave * 4352);
    float* ep1 = (float*)((char*)Bs + wave * 4352);
    const bool f32path = (splitk || of32);
#pragma unroll
    for (int p = 0; p < 8; ++p) {
        float* ep = (p & 1) ? ep1 : ep0;
#pragma unroll
        for (int n = 0; n < 4; ++n)
#pragma unroll
            for (int r = 0; r < 4; ++r)
                ep[(qd * 4 + r) * 68 + n * 16 + l15] = acc[p][n][r];
        WAIT_LGKM0();
        if (f32path) {
#pragma unroll
            for (int it = 0; it < 4; ++it) {
                const int idx = it * 64 + lane;
                const int row = idx >> 4;            // 0..15
                const int colc = (idx & 15) * 4;     // 0..60, step 4
                f32x4 v = *(const f32x4*)(ep + row * 68 + colc);
                const int gcol = bn * 256 + wn * 64 + colc;
                const bf16x4 bb = *(const bf16x4*)(bias + gcol);
                const int grow = bm * 256 + wm * 128 + p * 16 + row;
#pragma unroll
                for (int j = 0; j < 4; ++j) {
                    float bvj = (kpart == 0) ? us2f((unsigned short)bb[j]) : 0.f;
                    float vv = v[j] + bvj;
                    if (flags & FLAG_RELU) vv = fmaxf(vv, 0.f);
                    v[j] = vv;
                }
                *(f32x4*)(Cf + (size_t)grow * ldc + gcol) = v;
            }
        } else {
            // bf16 path: 2 iters, 8 cols/lane, 16-B stores
#pragma unroll
            for (int it = 0; it < 2; ++it) {
                const int unit = it * 64 + lane;
                const int row = unit >> 3;           // 0..15
                const int c8 = (unit & 7) * 8;       // 0..56, step 8
                f32x4 v0 = *(const f32x4*)(ep + row * 68 + c8);
                f32x4 v1 = *(const f32x4*)(ep + row * 68 + c8 + 4);
                const int gcol = bn * 256 + wn * 64 + c8;
                const bf16x8 bb = *(const bf16x8*)(bias + gcol);
                const int grow = bm * 256 + wm * 128 + p * 16 + row;
                bf16x8 h;
#pragma unroll
                for (int j = 0; j < 4; ++j) {
                    float a0 = v0[j] + us2f((unsigned short)bb[j]);
                    float a1 = v1[j] + us2f((unsigned short)bb[4 + j]);
                    if (flags & FLAG_RELU) {
                        a0 = fmaxf(a0, 0.f);
                        a1 = fmaxf(a1, 0.f);
                    }
                    h[j] = f2bs(a0);
                    h[4 + j] = f2bs(a1);
                }
                // QKV: an 8-col chunk never straddles a 1024-col boundary
                const size_t cbase = (flags & FLAG_QKV)
                    ? (size_t)(gcol >> 10) * (8192u * 1024u) + (gcol & 1023)
                    : (size_t)gcol;
                *(bf16x8*)(C + (size_t)grow * ldc + cbase) = h;
            }
        }
    }
}

// ---------------------------------------------------------------------------
// Flash attention, S^T formulation. Grid: 1024 linear blocks, 256 threads.
// XCD-locality remap: lin&7 = XCD chunk -> all 8 qt-blocks of one (b,h) on
// one XCD; its 16 (b,h) pairs x 256KB K/V = 4MB = the XCD L2.
// Softmax via exp2 with log2e folded into the fmaf constants.
// ---------------------------------------------------------------------------
__global__ __launch_bounds__(256) void attn_k(const bf16* __restrict__ Q,
                                              const bf16* __restrict__ Kc,
                                              const bf16* __restrict__ Vt,
                                              const bf16* __restrict__ mask,
                                              bf16* __restrict__ ctx) {
    const int S = 1024, D = 1024;
    __shared__ __align__(16) bf16 Ks[128 * KSTRIDE];  // 17.0 KB
    __shared__ __align__(16) bf16 Vs[64 * VSTRIDE];   // 16.5 KB
    const int tid = threadIdx.x, wave = tid >> 6, lane = tid & 63;
    const int qd = lane >> 4, l15 = lane & 15;
    // XCD-locality decomposition: hardware XCD = blockIdx.x % 8 (round-robin)
    const int lin = blockIdx.x;
    const int xcd = lin & 7;
    const int sub = lin >> 3;              // 0..127
    const int bh = xcd * 16 + (sub >> 3);  // 0..127, 16 (b,h) pairs per XCD
    const int qt = sub & 7;
    const int h = bh & 15, b = bh >> 4;
    const size_t baseBSD = (size_t)b * S * D;

    const bf16* gK[4]; bf16* sK[4];
    const bf16* gV[4]; bf16* sV[4];
#pragma unroll
    for (int i = 0; i < 4; i++) {
        int t = tid + i * 256;
        gK[i] = Kc + baseBSD + (size_t)(t >> 3) * D + h * 64 + (t & 7) * 8;
        sK[i] = Ks + (t >> 3) * KSTRIDE + (t & 7) * 8;
        gV[i] = Vt + ((size_t)b * D + h * 64 + (t >> 4)) * S + (t & 15) * 8;
        sV[i] = Vs + (t >> 4) * VSTRIDE + (t & 15) * 8;
    }

    bf16x8 aq[2][2];
#pragma unroll
    for (int mt = 0; mt < 2; mt++)
#pragma unroll
        for (int ks = 0; ks < 2; ks++) {
            int row = qt * 128 + wave * 32 + mt * 16 + l15;
            int col = h * 64 + ks * 32 + qd * 8;
            aq[mt][ks] = *(const bf16x8*)(Q + baseBSD + (size_t)row * D + col);
        }

    bf16x8 kreg[4], vreg[4];
#pragma unroll
    for (int i = 0; i < 4; i++) {
        kreg[i] = *(const bf16x8*)(gK[i]);
        vreg[i] = *(const bf16x8*)(gV[i]);
    }

    f32x4 OT[2][4] = {};
    float lacc[2] = {0.f, 0.f};

    for (int kt = 0; kt < 8; kt++) {
        __syncthreads();
#pragma unroll
        for (int i = 0; i < 4; i++) {
            *(bf16x8*)sK[i] = kreg[i];
            *(bf16x8*)sV[i] = vreg[i];
        }
        __syncthreads();
        const int ktn = (kt < 7) ? kt + 1 : 7;
#pragma unroll
        for (int i = 0; i < 4; i++) {
            kreg[i] = *(const bf16x8*)(gK[i] + (size_t)ktn * 128 * D);
            vreg[i] = *(const bf16x8*)(gV[i] + ktn * 128);
        }
        bf16x8 pb[2][4];
#pragma unroll
        for (int g = 0; g < 2; g++) {
            f32x4 s[2][4] = {};
#pragma unroll
            for (int ks = 0; ks < 2; ks++) {
                bf16x8 ak[4];
#pragma unroll
                for (int n2 = 0; n2 < 4; n2++) {
                    int nt = g * 4 + n2;
                    ak[n2] = *(const bf16x8*)(Ks + (nt * 16 + l15) * KSTRIDE +
                                              ks * 32 + qd * 8);
                }
#pragma unroll
                for (int mt = 0; mt < 2; mt++)
#pragma unroll
                    for (int n2 = 0; n2 < 4; n2++)
                        s[mt][n2] = MFMA16(ak[n2], aq[mt][ks], s[mt][n2]);
            }
#pragma unroll
            for (int n2 = 0; n2 < 4; n2++) {
                int nt = g * 4 + n2;
                ushort4 mu = *(const ushort4*)(mask + b * S + kt * 128 +
                                               nt * 16 + qd * 4);
                float mv[4];
                mv[0] = fmaf(SM_MASK2, us2f(mu.x), SM_SHIFT2);
                mv[1] = fmaf(SM_MASK2, us2f(mu.y), SM_SHIFT2);
                mv[2] = fmaf(SM_MASK2, us2f(mu.z), SM_SHIFT2);
                mv[3] = fmaf(SM_MASK2, us2f(mu.w), SM_SHIFT2);
#pragma unroll
                for (int mt = 0; mt < 2; mt++)
#pragma unroll
                    for (int r = 0; r < 4; r++) {
                        float p = exp2f(fmaf(s[mt][n2][r], SM_SCALE2, mv[r]));
                        s[mt][n2][r] = p;
                        lacc[mt] += p;
                    }
            }
#pragma unroll
            for (int mt = 0; mt < 2; mt++)
#pragma unroll
                for (int half = 0; half < 2; half++) {
                    bf16x8 p8;
#pragma unroll
                    for (int j = 0; j < 4; j++) {
                        p8[j] = f2bs(s[mt][2 * half][j]);
                        p8[4 + j] = f2bs(s[mt][2 * half + 1][j]);
                    }
                    pb[mt][g * 2 + half] = p8;
                }
        }
#pragma unroll
        for (int c = 0; c < 4; c++) {
            bf16x8 av[4];
#pragma unroll
            for (int dt = 0; dt < 4; dt++) {
                const bf16* vb = Vs + (dt * 16 + l15) * VSTRIDE + qd * 4;
                bf16x4 lo = *(const bf16x4*)(vb + (2 * c) * 16);
                bf16x4 hi = *(const bf16x4*)(vb + (2 * c + 1) * 16);
                av[dt] = __builtin_shufflevector(lo, hi, 0, 1, 2, 3, 4, 5, 6, 7);
            }
#pragma unroll
            for (int mt = 0; mt < 2; mt++)
#pragma unroll
                for (int dt = 0; dt < 4; dt++)
                    OT[mt][dt] = MFMA16(av[dt], pb[mt][c], OT[mt][dt]);
        }
    }
#pragma unroll
    for (int mt = 0; mt < 2; mt++) {
        float rs = lacc[mt];
        rs += __shfl_xor(rs, 16);
        rs += __shfl_xor(rs, 32);
        const float inv = 1.f / rs;
        const int row = qt * 128 + wave * 32 + mt * 16 + l15;
#pragma unroll
        for (int dt = 0; dt < 4; dt++) {
            bf16x4 st;
#pragma unroll
            for (int r = 0; r < 4; r++) st[r] = f2bs(OT[mt][dt][r] * inv);
            *(bf16x4*)(ctx + baseBSD + (size_t)row * D + h * 64 + dt * 16 +
                       qd * 4) = st;
        }
    }
}

// ---------------------------------------------------------------------------
// x1 = LayerNorm(X + Y) * g + be (bf16 out; X/out may alias row-wise).
// ---------------------------------------------------------------------------
__global__ __launch_bounds__(256) void ln_add(const bf16* X,
                                              const bf16* __restrict__ Y,
                                              const bf16* __restrict__ g,
                                              const bf16* __restrict__ be,
                                              bf16* out) {
    const int tid = threadIdx.x;
    const int row = blockIdx.x;
    const size_t base = (size_t)row * 1024 + tid * 4;
    float v[4];
#pragma unroll
    for (int i = 0; i < 4; i++) v[i] = b2f(X[base + i]) + b2f(Y[base + i]);
    float s1 = 0.f, s2 = 0.f;
#pragma unroll
    for (int i = 0; i < 4; i++) {
        s1 += v[i];
        s2 += v[i] * v[i];
    }
    for (int off = 32; off; off >>= 1) {
        s1 += __shfl_xor(s1, off);
        s2 += __shfl_xor(s2, off);
    }
    __shared__ float red[8];
    const int wave = tid >> 6, lane = tid & 63;
    if (lane == 0) {
        red[wave] = s1;
        red[4 + wave] = s2;
    }
    __syncthreads();
    s1 = red[0] + red[1] + red[2] + red[3];
    s2 = red[4] + red[5] + red[6] + red[7];
    const float mu = s1 * (1.f / 1024.f);
    const float var = s2 * (1.f / 1024.f) - mu * mu;
    const float rstd = rsqrtf(var + 1e-6f);
    bf16 oh[4];
#pragma unroll
    for (int i = 0; i < 4; i++) {
        float gg = b2f(g[tid * 4 + i]);
        float bb = b2f(be[tid * 4 + i]);
        oh[i] = f2b(gg * (v[i] - mu) * rstd + bb);
    }
    *(ushort4*)(out + base) = *(ushort4*)oh;
}

// ---------------------------------------------------------------------------
// x1 = LayerNorm(X + P0 + P1) * g + be; P0/P1 fp32 split-K partials.
// ---------------------------------------------------------------------------
__global__ __launch_bounds__(256) void ln_add2f(const bf16* X,
                                                const float* __restrict__ P0,
                                                const float* __restrict__ P1,
                                                const bf16* __restrict__ g,
                                                const bf16* __restrict__ be,
                                                bf16* out) {
    const int tid = threadIdx.x;
    const int row = blockIdx.x;
    const size_t base = (size_t)row * 1024 + tid * 4;
    float4 p0 = *(const float4*)(P0 + base);
    float4 p1 = *(const float4*)(P1 + base);
    float v[4];
    v[0] = b2f(X[base + 0]) + p0.x + p1.x;
    v[1] = b2f(X[base + 1]) + p0.y + p1.y;
    v[2] = b2f(X[base + 2]) + p0.z + p1.z;
    v[3] = b2f(X[base + 3]) + p0.w + p1.w;
    float s1 = 0.f, s2 = 0.f;
#pragma unroll
    for (int i = 0; i < 4; i++) {
        s1 += v[i];
        s2 += v[i] * v[i];
    }
    for (int off = 32; off; off >>= 1) {
        s1 += __shfl_xor(s1, off);
        s2 += __shfl_xor(s2, off);
    }
    __shared__ float red[8];
    const int wave = tid >> 6, lane = tid & 63;
    if (lane == 0) {
        red[wave] = s1;
        red[4 + wave] = s2;
    }
    __syncthreads();
    s1 = red[0] + red[1] + red[2] + red[3];
    s2 = red[4] + red[5] + red[6] + red[7];
    const float mu = s1 * (1.f / 1024.f);
    const float var = s2 * (1.f / 1024.f) - mu * mu;
    const float rstd = rsqrtf(var + 1e-6f);
    bf16 oh[4];
#pragma unroll
    for (int i = 0; i < 4; i++) {
        float gg = b2f(g[tid * 4 + i]);
        float bb = b2f(be[tid * 4 + i]);
        oh[i] = f2b(gg * (v[i] - mu) * rstd + bb);
    }
    *(ushort4*)(out + base) = *(ushort4*)oh;
}

// ---------------------------------------------------------------------------
// Final LN: X bf16; Y = y2 living in d_out (fp32 if *flag else bf16);
// writes d_out in-place in the harness dtype.
// ---------------------------------------------------------------------------
__global__ __launch_bounds__(256) void ln_add_out(const bf16* __restrict__ X,
                                                  const void* Yv,
                                                  const bf16* __restrict__ g,
                                                  const bf16* __restrict__ be,
                                                  void* out,
                                                  const int* __restrict__ flag) {
    const int tid = threadIdx.x;
    const int row = blockIdx.x;
    const size_t base = (size_t)row * 1024 + tid * 4;
    const int f = *flag;
    float v[4];
    if (f) {
        float4 y = *(const float4*)((const float*)Yv + base);
        v[0] = b2f(X[base + 0]) + y.x;
        v[1] = b2f(X[base + 1]) + y.y;
        v[2] = b2f(X[base + 2]) + y.z;
        v[3] = b2f(X[base + 3]) + y.w;
    } else {
        const bf16* Yh = (const bf16*)Yv;
#pragma unroll
        for (int i = 0; i < 4; i++) v[i] = b2f(X[base + i]) + b2f(Yh[base + i]);
    }
    float s1 = 0.f, s2 = 0.f;
#pragma unroll
    for (int i = 0; i < 4; i++) {
        s1 += v[i];
        s2 += v[i] * v[i];
    }
    for (int off = 32; off; off >>= 1) {
        s1 += __shfl_xor(s1, off);
        s2 += __shfl_xor(s2, off);
    }
    __shared__ float red[8];
    const int wave = tid >> 6, lane = tid & 63;
    if (lane == 0) {
        red[wave] = s1;
        red[4 + wave] = s2;
    }
    __syncthreads();
    s1 = red[0] + red[1] + red[2] + red[3];
    s2 = red[4] + red[5] + red[6] + red[7];
    const float mu = s1 * (1.f / 1024.f);
    const float var = s2 * (1.f / 1024.f) - mu * mu;
    const float rstd = rsqrtf(var + 1e-6f);
    float o[4];
#pragma unroll
    for (int i = 0; i < 4; i++) {
        float gg = b2f(g[tid * 4 + i]);
        float bb = b2f(be[tid * 4 + i]);
        o[i] = gg * (v[i] - mu) * rstd + bb;
    }
    if (f) {
        *(float4*)((float*)out + base) = make_float4(o[0], o[1], o[2], o[3]);
    } else {
        bf16 oh[4];
#pragma unroll
        for (int i = 0; i < 4; i++) oh[i] = f2b(o[i]);
        *(ushort4*)((bf16*)out + base) = *(ushort4*)oh;
    }
}

// ---------------------------------------------------------------------------
// Final LN, split-K variant: v = X + P0 + P1 (both fp32). P0 may alias out
// (row-aligned in-place is safe). Writes harness dtype per flag.
// ---------------------------------------------------------------------------
__global__ __launch_bounds__(256) void ln_add_out2f(const bf16* __restrict__ X,
                                                    const float* P0,
                                                    const float* __restrict__ P1,
                                                    const bf16* __restrict__ g,
                                                    const bf16* __restrict__ be,
                                                    void* out,
                                                    const int* __restrict__ flag) {
    const int tid = threadIdx.x;
    const int row = blockIdx.x;
    const size_t base = (size_t)row * 1024 + tid * 4;
    const int f = *flag;
    float4 p0 = *(const float4*)(P0 + base);
    float4 p1 = *(const float4*)(P1 + base);
    float v[4];
    v[0] = b2f(X[base + 0]) + p0.x + p1.x;
    v[1] = b2f(X[base + 1]) + p0.y + p1.y;
    v[2] = b2f(X[base + 2]) + p0.z + p1.z;
    v[3] = b2f(X[base + 3]) + p0.w + p1.w;
    float s1 = 0.f, s2 = 0.f;
#pragma unroll
    for (int i = 0; i < 4; i++) {
        s1 += v[i];
        s2 += v[i] * v[i];
    }
    for (int off = 32; off; off >>= 1) {
        s1 += __shfl_xor(s1, off);
        s2 += __shfl_xor(s2, off);
    }
    __shared__ float red[8];
    const int wave = tid >> 6, lane = tid & 63;
    if (lane == 0) {
        red[wave] = s1;
        red[4 + wave] = s2;
    }
    __syncthreads();
    s1 = red[0] + red[1] + red[2] + red[3];
    s2 = red[4] + red[5] + red[6] + red[7];
    const float mu = s1 * (1.f / 1024.f);
    const float var = s2 * (1.f / 1024.f) - mu * mu;
    const float rstd = rsqrtf(var + 1e-6f);
    float o[4];
#pragma unroll
    for (int i = 0; i < 4; i++) {
        float gg = b2f(g[tid * 4 + i]);
        float bb = b2f(be[tid * 4 + i]);
        o[i] = gg * (v[i] - mu) * rstd + bb;
    }
    if (f) {
        *(float4*)((float*)out + base) = make_float4(o[0], o[1], o[2], o[3]);
    } else {
        bf16 oh[4];
#pragma unroll
        for (int i = 0; i < 4; i++) oh[i] = f2b(o[i]);
        *(ushort4*)((bf16*)out + base) = *(ushort4*)oh;
    }
}

// ---------------------------------------------------------------------------
extern "C" void kernel_launch(void* const* d_in, const int* in_sizes, int n_in,
                              void* d_out, int out_size, void* d_ws, size_t ws_size,
                              hipStream_t stream) {
    const void* x = d_in[0];
    const void* mask = d_in[1];
    const void* Wq = d_in[2];
    const void* bq = d_in[3];
    const void* Wk = d_in[4];
    const void* bk = d_in[5];
    const void* Wv = d_in[6];
    const void* bv = d_in[7];
    const void* Wo = d_in[8];
    const void* bo = d_in[9];
    const void* g1 = d_in[10];
    const void* be1 = d_in[11];
    const void* W1 = d_in[12];
    const void* bf1 = d_in[13];
    const void* W2 = d_in[14];
    const void* bf2 = d_in[15];
    const void* g2 = d_in[16];
    const void* be2 = d_in[17];

    char* ws = (char*)d_ws;
    const size_t MB = 1u << 20;
    const size_t KB = 1u << 10;
    // --- workspace base layout (high-water 88.05 MB without split) ---
    bf16* WqkvT = (bf16*)(ws + 0 * MB);  // [3072][1024] (Wq|Wk|Wv), 6 MB
    bf16* WoT = (bf16*)(ws + 6 * MB);    // 2 MB
    bf16* xc = (bf16*)(ws + 8 * MB);     // 16 MB; becomes x1 in-place (step 6)
    bf16* Qb = (bf16*)(ws + 24 * MB);    // 16 MB
    bf16* Kb = (bf16*)(ws + 40 * MB);    // 16 MB
    bf16* Vb = (bf16*)(ws + 56 * MB);    // 16 MB
    bf16* Vtb = (bf16*)(ws + 72 * MB);   // 16 MB
    char* sm = ws + 88 * MB;
    int* flag = (int*)(sm + 0);
    bf16* mask_c = (bf16*)(sm + 4 * KB);
    bf16* bqkv_c = (bf16*)(sm + 20 * KB);
    bf16* bo_c = (bf16*)(sm + 26 * KB);
    bf16* bf1_c = (bf16*)(sm + 28 * KB);
    bf16* bf2_c = (bf16*)(sm + 36 * KB);
    bf16* g1_c = (bf16*)(sm + 38 * KB);
    bf16* be1_c = (bf16*)(sm + 40 * KB);
    bf16* g2_c = (bf16*)(sm + 42 * KB);
    bf16* be2_c = (bf16*)(sm + 44 * KB);
    // aliases (stream-order safe):
    bf16* yb = Qb;                      // step 5 out (Q dead after attn)
    bf16* ctxb = Vb;                    // step 4 out (V dead after Vt)
    bf16* x1b = xc;                     // step 6: LN in-place over xc
    bf16* W1T = (bf16*)(ws + 0 * MB);   // step 6.5 (QKV/Wo weights dead), 8 MB
    bf16* W2T = (bf16*)(ws + 0 * MB);   // step 7.5 (W1T dead), 8 MB
    bf16* hb = Qb;                      // step 7: 24-88 MB (64 MB, all dead)
    // --- split-K extension (guarded): pk1 = fp32 partial at 89-121 MB ---
    float* pk1 = (float*)(ws + 89 * MB);
    float* yw0 = (float*)Qb;            // Wo partial0, fp32 32 MB over 24-56 (Q,K dead)
    const bool f32out = (out_size >= 32 * 1024 * 1024);
    // FFN2 partial0: d_out if fp32 harness, else extra ws at 121-153 MB
    float* p0f = f32out ? (float*)d_out : (float*)(ws + 121 * MB);
    const size_t need_ws = f32out ? 121 * MB + 32 * MB : 153 * MB + 32 * MB;
    const bool do_split = (ws_size >= need_ws);

    dim3 blk(256);
    dim3 blk5(512);
    // 0. dtype detect + conversions
    detect_k<<<dim3(1), blk, 0, stream>>>((const unsigned short*)x, flag);
    cvt_k<<<dim3(8192), blk, 0, stream>>>(x, xc, 8388608, flag);
    CvtBatch cb;
    cb.src[0] = mask;  cb.dst[0] = mask_c;        cb.n[0] = 8192;
    cb.src[1] = bq;    cb.dst[1] = bqkv_c;        cb.n[1] = 1024;
    cb.src[2] = bk;    cb.dst[2] = bqkv_c + 1024; cb.n[2] = 1024;
    cb.src[3] = bv;    cb.dst[3] = bqkv_c + 2048; cb.n[3] = 1024;
    cb.src[4] = bo;    cb.dst[4] = bo_c;          cb.n[4] = 1024;
    cb.src[5] = bf1;   cb.dst[5] = bf1_c;         cb.n[5] = 4096;
    cb.src[6] = bf2;   cb.dst[6] = bf2_c;         cb.n[6] = 1024;
    cb.src[7] = g1;    cb.dst[7] = g1_c;          cb.n[7] = 1024;
    cb.src[8] = be1;   cb.dst[8] = be1_c;         cb.n[8] = 1024;
    cb.src[9] = g2;    cb.dst[9] = g2_c;          cb.n[9] = 1024;
    cb.src[10] = be2;  cb.dst[10] = be2_c;        cb.n[10] = 1024;
    cvt_small_k<<<dim3(11), blk, 0, stream>>>(cb, flag);
    // 1. attention weight transposes
    transpose_k<<<dim3(16, 16, 1), blk, 0, stream>>>(Wq, WqkvT, 1024, 1024, flag);
    transpose_k<<<dim3(16, 16, 1), blk, 0, stream>>>(Wk, WqkvT + 1024 * 1024, 1024, 1024, flag);
    transpose_k<<<dim3(16, 16, 1), blk, 0, stream>>>(Wv, WqkvT + 2048 * 1024, 1024, 1024, flag);
    transpose_k<<<dim3(16, 16, 1), blk, 0, stream>>>(Wo, WoT, 1024, 1024, flag);
    // 2. fused QKV projection (N=3072, epilogue splits into Qb/Kb/Vb); 384 wgs
    gemm256<<<dim3(384), blk5, 0, stream>>>(xc, 1024, WqkvT, 1024, bqkv_c, Qb, 1024, 8192, 3072, 1024, FLAG_QKV, nullptr, nullptr);
    // 3. V -> Vt[b, d, s]
    transpose_k<<<dim3(16, 16, 8), blk, 0, stream>>>(Vb, Vtb, 1024, 1024, nullptr);
    // 4. attention -> ctx (1024 linear blocks, XCD-locality remap)
    attn_k<<<dim3(1024), blk, 0, stream>>>(Qb, Kb, Vtb, mask_c, ctxb);
    // 5+6. y = ctx @ Wo + bo ; x1 = LN(x + y)
    if (do_split) {
        // split-K x2: 256 wgs, partials fp32 (yw0 over dead Q/K, pk1 at 89 MB)
        gemm256<<<dim3(256), blk5, 0, stream>>>(ctxb, 1024, WoT, 1024, bo_c, yw0, 1024, 8192, 1024, 1024, FLAG_SPLITK, nullptr, pk1);
        ln_add2f<<<dim3(8192), blk, 0, stream>>>(xc, yw0, pk1, g1_c, be1_c, x1b);
    } else {
        gemm256<<<dim3(128), blk5, 0, stream>>>(ctxb, 1024, WoT, 1024, bo_c, yb, 1024, 8192, 1024, 1024, 0, nullptr, nullptr);
        ln_add<<<dim3(8192), blk, 0, stream>>>(xc, yb, g1_c, be1_c, x1b);
    }
    // 6.5 W1T into 0-8 MB (QKV/Wo weights dead)
    transpose_k<<<dim3(64, 16, 1), blk, 0, stream>>>(W1, W1T, 1024, 4096, flag);
    // 7. h = relu(x1 @ W1 + bf1), N=4096, hb = 24-88 MB; 512 wgs (2 rounds)
    gemm256<<<dim3(512), blk5, 0, stream>>>(x1b, 1024, W1T, 1024, bf1_c, hb, 4096, 8192, 4096, 1024, FLAG_RELU, nullptr, nullptr);
    // 7.5 W2T into 0-8 MB (W1T dead)
    transpose_k<<<dim3(16, 64, 1), blk, 0, stream>>>(W2, W2T, 4096, 1024, flag);
    // 8+9. y2 = h @ W2 + bf2 ; out = LN(x1 + y2)
    if (do_split) {
        gemm256<<<dim3(256), blk5, 0, stream>>>(hb, 4096, W2T, 4096, bf2_c, p0f, 1024, 8192, 1024, 4096, FLAG_SPLITK, nullptr, pk1);
        ln_add_out2f<<<dim3(8192), blk, 0, stream>>>(x1b, p0f, pk1, g2_c, be2_c, d_out, flag);
    } else {
        gemm256<<<dim3(128), blk5, 0, stream>>>(hb, 4096, W2T, 4096, bf2_c, d_out, 1024, 8192, 1024, 4096, FLAG_OUTF32, flag, nullptr);
        ln_add_out<<<dim3(8192), blk, 0, stream>>>(x1b, d_out, g2_c, be2_c, d_out, flag);
    }
}

// Round 7
// 578.618 us; speedup vs baseline: 1.0302x; 1.0302x over previous
//
#include <hip/hip_runtime.h>
#include <hip/hip_bf16.h>
#include <math.h>

// ---------------------------------------------------------------------------
// EncoderBlock on MI355X (gfx950). B=8, S=1024, D=1024, H=16, DH=64, F=4096.
// Round 14: fix round-13 regression. exp2f() is OCML correctly-rounded (range
// reduction, ~10+ VALU ops) -- NOT the v_exp_f32 instruction; attn went
// 80->103 us. Replace with __builtin_amdgcn_exp2f (raw v_exp_f32) keeping
// the folded-log2e constants: one v_exp per probability, one v_mul fewer
// than the __expf baseline. gemm256 epilogue ping-pong (round 13, mildly
// positive) retained; XCD remap (r12) + split-K (r11) retained.
// ---------------------------------------------------------------------------

typedef __hip_bfloat16 bf16;
typedef short bf16x8 __attribute__((ext_vector_type(8)));   // MFMA A/B frag (8 bf16)
typedef short bf16x4 __attribute__((ext_vector_type(4)));   // half-frag (8 B)
typedef float f32x4 __attribute__((ext_vector_type(4)));    // MFMA C/D frag

typedef unsigned int __attribute__((address_space(1))) as1_uint;
typedef unsigned int __attribute__((address_space(3))) as3_uint;

#define MFMA16(a, b, c) __builtin_amdgcn_mfma_f32_16x16x32_bf16((a), (b), (c), 0, 0, 0)
#define FLAG_RELU 1
#define FLAG_QKV 4
#define FLAG_OUTF32 8
#define FLAG_SPLITK 16
#define KSTRIDE 68    // K-tile row stride (dh 64 + 4 pad)
#define VSTRIDE 132   // V-tile row stride (s 128 + 4 pad)
// exp2-folded softmax constants (LOG2E = 1.44269504)
#define SM_SCALE2 0.18033688f      // 0.125 * log2e
#define SM_MASK2 -1.44269504e9f    // -1e9 * log2e
#define SM_SHIFT2 -28.8539008f     // -20 * log2e

// compiler-fenced raw barrier (no implicit vmcnt(0) drain like __syncthreads)
#define BAR() do { asm volatile("" ::: "memory"); \
    __builtin_amdgcn_s_barrier(); \
    asm volatile("" ::: "memory"); } while (0)
#define WAIT_LGKM0() do { asm volatile("s_waitcnt lgkmcnt(0)" ::: "memory"); \
    __builtin_amdgcn_sched_barrier(0); } while (0)
#define WAIT_VM4() do { asm volatile("s_waitcnt vmcnt(4)" ::: "memory"); \
    __builtin_amdgcn_sched_barrier(0); } while (0)
#define WAIT_VM0() do { asm volatile("s_waitcnt vmcnt(0)" ::: "memory"); \
    __builtin_amdgcn_sched_barrier(0); } while (0)

__device__ __forceinline__ float b2f(bf16 v) { return __bfloat162float(v); }
__device__ __forceinline__ bf16 f2b(float v) { return __float2bfloat16(v); }
__device__ __forceinline__ short f2bs(float v) {
    union { bf16 h; short s; } u;
    u.h = f2b(v);
    return u.s;
}
__device__ __forceinline__ float us2f(unsigned short u) {
    return __uint_as_float(((unsigned int)u) << 16);
}

__device__ __forceinline__ void async_copy16(void* lds, const void* gp) {
    __builtin_amdgcn_global_load_lds((const as1_uint*)gp, (as3_uint*)lds, 16, 0, 0);
}

// ---------------------------------------------------------------------------
// Input dtype detector (flag=1 -> inputs are float32).
// ---------------------------------------------------------------------------
__global__ void detect_k(const unsigned short* __restrict__ xs, int* flag) {
    __shared__ int vote;
    if (threadIdx.x == 0) vote = 0;
    __syncthreads();
    int bad = 0;
    for (int i = threadIdx.x; i < 16384; i += 256) {
        int e = (xs[i] >> 7) & 0xFF;
        if (e >= 0x84) bad = 1;
    }
    if (bad) atomicOr(&vote, 1);
    __syncthreads();
    if (threadIdx.x == 0) *flag = vote;
}

// ---------------------------------------------------------------------------
// Convert large tensor to bf16.
// ---------------------------------------------------------------------------
__global__ __launch_bounds__(256) void cvt_k(const void* __restrict__ in,
                                             bf16* __restrict__ out, int n,
                                             const int* __restrict__ flag) {
    const int f = *flag;
    const int base = (blockIdx.x * 256 + threadIdx.x) * 4;
    if (f) {
        const float* p = (const float*)in;
#pragma unroll
        for (int j = 0; j < 4; j++) {
            int i = base + j;
            if (i < n) out[i] = f2b(p[i]);
        }
    } else {
        const bf16* p = (const bf16*)in;
#pragma unroll
        for (int j = 0; j < 4; j++) {
            int i = base + j;
            if (i < n) out[i] = p[i];
        }
    }
}

// ---------------------------------------------------------------------------
// Batched conversion of the 11 small tensors (one block per tensor).
// ---------------------------------------------------------------------------
struct CvtBatch {
    const void* src[11];
    bf16* dst[11];
    int n[11];
};
__global__ __launch_bounds__(256) void cvt_small_k(CvtBatch cb,
                                                   const int* __restrict__ flag) {
    const int f = *flag;
    const int seg = blockIdx.x;
    const int n = cb.n[seg];
    const void* in = cb.src[seg];
    bf16* out = cb.dst[seg];
    if (f) {
        const float* p = (const float*)in;
        for (int i = threadIdx.x; i < n; i += 256) out[i] = f2b(p[i]);
    } else {
        const bf16* p = (const bf16*)in;
        for (int i = threadIdx.x; i < n; i += 256) out[i] = p[i];
    }
}

// ---------------------------------------------------------------------------
// Transpose: out[z][C][R] = in[z][R][C]. flag-aware read (nullptr = bf16).
// ---------------------------------------------------------------------------
__global__ __launch_bounds__(256) void transpose_k(const void* __restrict__ in,
                                                   bf16* __restrict__ out,
                                                   int R, int C,
                                                   const int* __restrict__ flag) {
    __shared__ bf16 tile[64][65];
    const int f = flag ? *flag : 0;
    const int tid = threadIdx.x;
    const size_t zoff = (size_t)blockIdx.z * R * C;
    const int tr = blockIdx.y * 64, tc = blockIdx.x * 64;
#pragma unroll
    for (int i = 0; i < 16; i++) {
        int idx = i * 256 + tid;
        int r = idx >> 6, c = idx & 63;
        size_t g = zoff + (size_t)(tr + r) * C + tc + c;
        tile[r][c] = f ? f2b(((const float*)in)[g]) : ((const bf16*)in)[g];
    }
    __syncthreads();
#pragma unroll
    for (int i = 0; i < 16; i++) {
        int idx = i * 256 + tid;
        int r = idx >> 6, c = idx & 63;
        out[zoff + (size_t)(tc + r) * R + tr + c] = tile[c][r];
    }
}

// ---------------------------------------------------------------------------
// 256x256 8-phase GEMM: C[M,N](ldc) = A[M,K](lda) @ Bt[N,K](ldb)^T + bias.
// 512 threads = 8 waves (2M x 4N), per-wave 128x64 output (acc[8][4]), BK=64.
// T2 swizzle + T3/T4 counted-vmcnt pipeline + T5 setprio (see round 8/9).
// FLAG_SPLITK: grid = 2*(M/256)*(N/256); kpart = swz&1 selects K-half;
// fp32 partial to Cv (kpart0, +bias) / Cv2 (kpart1, no bias). No RELU.
// Epilogue: wave-private scratch ping-pongs between dead As/Bs (no per-pass
// lgkm drain); bf16 path stores 16 B/lane. Requires M%256==0, N%256==0,
// K%64==0 (K%128==0 if split), nwg%8==0.
// ---------------------------------------------------------------------------
__global__ __launch_bounds__(512, 2) void gemm256(const bf16* __restrict__ A, int lda,
                                                  const bf16* __restrict__ Bt, int ldb,
                                                  const bf16* __restrict__ bias,
                                                  void* __restrict__ Cv, int ldc,
                                                  int M, int N, int K, int flags,
                                                  const int* __restrict__ dtf,
                                                  void* __restrict__ Cv2) {
    __shared__ __align__(16) bf16 As[2][256 * 64];   // 64 KiB
    __shared__ __align__(16) bf16 Bs[2][256 * 64];   // 64 KiB
    const int tid = threadIdx.x;
    const int wave = tid >> 6, lane = tid & 63;
    const int qd = lane >> 4, l15 = lane & 15;
    const int wm = wave >> 2, wn = wave & 3;         // 2 x 4 wave grid

    // XCD-aware block swizzle (nwg is a multiple of 8 for all our shapes)
    const int NB = N >> 8;
    const int cpx = gridDim.x >> 3;
    const int swz = ((int)blockIdx.x & 7) * cpx + ((int)blockIdx.x >> 3);
    const int splitk = flags & FLAG_SPLITK;
    const int kpart = splitk ? (swz & 1) : 0;
    const int tileIdx = splitk ? (swz >> 1) : swz;
    const int bn = tileIdx % NB, bm = tileIdx / NB;
    const int Keff = splitk ? (K >> 1) : K;
    const int koff = kpart ? Keff : 0;

    // ---- staging: pre-swizzled global source, linear LDS dest ----
    const int srow = tid >> 3;                        // 0..63 (row in sweep)
    const int schunk = (tid & 7) ^ (srow & 7);        // XOR-swizzled k-chunk
    const bf16* gA = A + (size_t)(bm * 256 + srow) * lda + koff + schunk * 8;
    const bf16* gB = Bt + (size_t)(bn * 256 + srow) * ldb + koff + schunk * 8;
    char* lA = (char*)As + wave * 1024;
    char* lB = (char*)Bs + wave * 1024;

    auto stA = [&](int d, int h, int tt) {
        const bf16* g = gA + (size_t)(h * 128) * lda + tt * 64;
        char* l = lA + d * 32768 + h * 16384;
        async_copy16(l, g);
        async_copy16(l + 8192, g + (size_t)64 * lda);
    };
    auto stB = [&](int d, int h, int tt) {
        const bf16* g = gB + (size_t)(h * 128) * ldb + tt * 64;
        char* l = lB + d * 32768 + h * 16384;
        async_copy16(l, g);
        async_copy16(l + 8192, g + (size_t)64 * ldb);
    };

    // ---- swizzled ds_read offsets (bytes). row&7 == l15&7 for all frags ----
    const int sx = l15 & 7;
    const char* pA = (const char*)As + (wm * 128 + l15) * 128;
    const char* pB = (const char*)Bs + (wn * 64 + l15) * 128;
    const int c0 = ((0 + qd) ^ sx) * 16;   // kk=0: global chunk qd
    const int c1 = ((4 + qd) ^ sx) * 16;   // kk=1: global chunk 4+qd

    f32x4 acc[8][4] = {};
    bf16x8 af[4][2], bfr[4][2];
    const int nt = Keff >> 6;

    // ---- prologue: tile 0 fully + B0/A0 of tile 1 in flight ----
    stA(0, 0, 0); stA(0, 1, 0); stB(0, 0, 0); stB(0, 1, 0);
    if (nt > 1) {
        stB(1, 0, 1); stA(1, 0, 1);
        WAIT_VM4();
    } else {
        WAIT_VM0();
    }
    BAR();

#pragma unroll 2
    for (int t = 0; t < nt; ++t) {
        const int d = t & 1, dn = d ^ 1;
        const int db = d * 32768;
        // ---------- phase 1: quadrant (m0-3, n0-1); 12 ds_reads ----------
#pragma unroll
        for (int m = 0; m < 4; ++m) {
            af[m][0] = *(const bf16x8*)(pA + db + m * 2048 + c0);
            af[m][1] = *(const bf16x8*)(pA + db + m * 2048 + c1);
        }
#pragma unroll
        for (int n = 0; n < 2; ++n) {
            bfr[n][0] = *(const bf16x8*)(pB + db + n * 2048 + c0);
            bfr[n][1] = *(const bf16x8*)(pB + db + n * 2048 + c1);
        }
        if (t + 1 < nt) stB(dn, 1, t + 1);
        BAR();
        WAIT_LGKM0();
        __builtin_amdgcn_s_setprio(1);
#pragma unroll
        for (int kk = 0; kk < 2; ++kk)
#pragma unroll
            for (int m = 0; m < 4; ++m)
#pragma unroll
                for (int n = 0; n < 2; ++n)
                    acc[m][n] = MFMA16(af[m][kk], bfr[n][kk], acc[m][n]);
        __builtin_amdgcn_s_setprio(0);
        BAR();
        // ---------- phase 2: quadrant (m0-3, n2-3); 4 ds_reads ----------
#pragma unroll
        for (int n = 0; n < 2; ++n) {
            bfr[2 + n][0] = *(const bf16x8*)(pB + db + (2 + n) * 2048 + c0);
            bfr[2 + n][1] = *(const bf16x8*)(pB + db + (2 + n) * 2048 + c1);
        }
        if (t + 1 < nt) stA(dn, 1, t + 1);
        BAR();
        WAIT_LGKM0();
        __builtin_amdgcn_s_setprio(1);
#pragma unroll
        for (int kk = 0; kk < 2; ++kk)
#pragma unroll
            for (int m = 0; m < 4; ++m)
#pragma unroll
                for (int n = 0; n < 2; ++n)
                    acc[m][2 + n] = MFMA16(af[m][kk], bfr[2 + n][kk], acc[m][2 + n]);
        __builtin_amdgcn_s_setprio(0);
        BAR();
        // ---------- phase 3: quadrant (m4-7, n0-1); 8 ds_reads ----------
#pragma unroll
        for (int m = 0; m < 4; ++m) {
            af[m][0] = *(const bf16x8*)(pA + db + (4 + m) * 2048 + c0);
            af[m][1] = *(const bf16x8*)(pA + db + (4 + m) * 2048 + c1);
        }
        if (t + 2 < nt) stB(d, 0, t + 2);
        BAR();
        WAIT_LGKM0();
        __builtin_amdgcn_s_setprio(1);
#pragma unroll
        for (int kk = 0; kk < 2; ++kk)
#pragma unroll
            for (int m = 0; m < 4; ++m)
#pragma unroll
                for (int n = 0; n < 2; ++n)
                    acc[4 + m][n] = MFMA16(af[m][kk], bfr[n][kk], acc[4 + m][n]);
        __builtin_amdgcn_s_setprio(0);
        BAR();
        // ---------- phase 4: quadrant (m4-7, n2-3); no ds_reads ----------
        if (t + 2 < nt) stA(d, 0, t + 2);
        BAR();
        __builtin_amdgcn_s_setprio(1);
#pragma unroll
        for (int kk = 0; kk < 2; ++kk)
#pragma unroll
            for (int m = 0; m < 4; ++m)
#pragma unroll
                for (int n = 0; n < 2; ++n)
                    acc[4 + m][2 + n] = MFMA16(af[m][kk], bfr[2 + n][kk], acc[4 + m][2 + n]);
        __builtin_amdgcn_s_setprio(0);
        // counted wait: everything tile t+1 needs has landed; only the
        // newest 4 loads (B0/A0 of tile t+2) may stay in flight.
        if (t + 2 < nt) {
            WAIT_VM4();
        } else {
            WAIT_VM0();
        }
        BAR();
    }

    // ---- epilogue: ping-pong wave-private LDS bounce -> wide stores ----
    const int of32 = (flags & FLAG_OUTF32) ? *dtf : 0;
    bf16* C = (bf16*)Cv;
    float* Cf = (float*)(kpart ? Cv2 : Cv);
    float* ep0 = (float*)((char*)As + wave * 4352);
    float* ep1 = (float*)((char*)Bs + wave * 4352);
    const bool f32path = (splitk || of32);
#pragma unroll
    for (int p = 0; p < 8; ++p) {
        float* ep = (p & 1) ? ep1 : ep0;
#pragma unroll
        for (int n = 0; n < 4; ++n)
#pragma unroll
            for (int r = 0; r < 4; ++r)
                ep[(qd * 4 + r) * 68 + n * 16 + l15] = acc[p][n][r];
        WAIT_LGKM0();
        if (f32path) {
#pragma unroll
            for (int it = 0; it < 4; ++it) {
                const int idx = it * 64 + lane;
                const int row = idx >> 4;            // 0..15
                const int colc = (idx & 15) * 4;     // 0..60, step 4
                f32x4 v = *(const f32x4*)(ep + row * 68 + colc);
                const int gcol = bn * 256 + wn * 64 + colc;
                const bf16x4 bb = *(const bf16x4*)(bias + gcol);
                const int grow = bm * 256 + wm * 128 + p * 16 + row;
#pragma unroll
                for (int j = 0; j < 4; ++j) {
                    float bvj = (kpart == 0) ? us2f((unsigned short)bb[j]) : 0.f;
                    float vv = v[j] + bvj;
                    if (flags & FLAG_RELU) vv = fmaxf(vv, 0.f);
                    v[j] = vv;
                }
                *(f32x4*)(Cf + (size_t)grow * ldc + gcol) = v;
            }
        } else {
            // bf16 path: 2 iters, 8 cols/lane, 16-B stores
#pragma unroll
            for (int it = 0; it < 2; ++it) {
                const int unit = it * 64 + lane;
                const int row = unit >> 3;           // 0..15
                const int c8 = (unit & 7) * 8;       // 0..56, step 8
                f32x4 v0 = *(const f32x4*)(ep + row * 68 + c8);
                f32x4 v1 = *(const f32x4*)(ep + row * 68 + c8 + 4);
                const int gcol = bn * 256 + wn * 64 + c8;
                const bf16x8 bb = *(const bf16x8*)(bias + gcol);
                const int grow = bm * 256 + wm * 128 + p * 16 + row;
                bf16x8 h;
#pragma unroll
                for (int j = 0; j < 4; ++j) {
                    float a0 = v0[j] + us2f((unsigned short)bb[j]);
                    float a1 = v1[j] + us2f((unsigned short)bb[4 + j]);
                    if (flags & FLAG_RELU) {
                        a0 = fmaxf(a0, 0.f);
                        a1 = fmaxf(a1, 0.f);
                    }
                    h[j] = f2bs(a0);
                    h[4 + j] = f2bs(a1);
                }
                // QKV: an 8-col chunk never straddles a 1024-col boundary
                const size_t cbase = (flags & FLAG_QKV)
                    ? (size_t)(gcol >> 10) * (8192u * 1024u) + (gcol & 1023)
                    : (size_t)gcol;
                *(bf16x8*)(C + (size_t)grow * ldc + cbase) = h;
            }
        }
    }
}

// ---------------------------------------------------------------------------
// Flash attention, S^T formulation. Grid: 1024 linear blocks, 256 threads.
// XCD-locality remap: lin&7 = XCD chunk -> all 8 qt-blocks of one (b,h) on
// one XCD; its 16 (b,h) pairs x 256KB K/V = 4MB = the XCD L2.
// Softmax: one v_exp_f32 per probability (__builtin_amdgcn_exp2f, folded
// log2e constants).
// ---------------------------------------------------------------------------
__global__ __launch_bounds__(256) void attn_k(const bf16* __restrict__ Q,
                                              const bf16* __restrict__ Kc,
                                              const bf16* __restrict__ Vt,
                                              const bf16* __restrict__ mask,
                                              bf16* __restrict__ ctx) {
    const int S = 1024, D = 1024;
    __shared__ __align__(16) bf16 Ks[128 * KSTRIDE];  // 17.0 KB
    __shared__ __align__(16) bf16 Vs[64 * VSTRIDE];   // 16.5 KB
    const int tid = threadIdx.x, wave = tid >> 6, lane = tid & 63;
    const int qd = lane >> 4, l15 = lane & 15;
    // XCD-locality decomposition: hardware XCD = blockIdx.x % 8 (round-robin)
    const int lin = blockIdx.x;
    const int xcd = lin & 7;
    const int sub = lin >> 3;              // 0..127
    const int bh = xcd * 16 + (sub >> 3);  // 0..127, 16 (b,h) pairs per XCD
    const int qt = sub & 7;
    const int h = bh & 15, b = bh >> 4;
    const size_t baseBSD = (size_t)b * S * D;

    const bf16* gK[4]; bf16* sK[4];
    const bf16* gV[4]; bf16* sV[4];
#pragma unroll
    for (int i = 0; i < 4; i++) {
        int t = tid + i * 256;
        gK[i] = Kc + baseBSD + (size_t)(t >> 3) * D + h * 64 + (t & 7) * 8;
        sK[i] = Ks + (t >> 3) * KSTRIDE + (t & 7) * 8;
        gV[i] = Vt + ((size_t)b * D + h * 64 + (t >> 4)) * S + (t & 15) * 8;
        sV[i] = Vs + (t >> 4) * VSTRIDE + (t & 15) * 8;
    }

    bf16x8 aq[2][2];
#pragma unroll
    for (int mt = 0; mt < 2; mt++)
#pragma unroll
        for (int ks = 0; ks < 2; ks++) {
            int row = qt * 128 + wave * 32 + mt * 16 + l15;
            int col = h * 64 + ks * 32 + qd * 8;
            aq[mt][ks] = *(const bf16x8*)(Q + baseBSD + (size_t)row * D + col);
        }

    bf16x8 kreg[4], vreg[4];
#pragma unroll
    for (int i = 0; i < 4; i++) {
        kreg[i] = *(const bf16x8*)(gK[i]);
        vreg[i] = *(const bf16x8*)(gV[i]);
    }

    f32x4 OT[2][4] = {};
    float lacc[2] = {0.f, 0.f};

    for (int kt = 0; kt < 8; kt++) {
        __syncthreads();
#pragma unroll
        for (int i = 0; i < 4; i++) {
            *(bf16x8*)sK[i] = kreg[i];
            *(bf16x8*)sV[i] = vreg[i];
        }
        __syncthreads();
        const int ktn = (kt < 7) ? kt + 1 : 7;
#pragma unroll
        for (int i = 0; i < 4; i++) {
            kreg[i] = *(const bf16x8*)(gK[i] + (size_t)ktn * 128 * D);
            vreg[i] = *(const bf16x8*)(gV[i] + ktn * 128);
        }
        bf16x8 pb[2][4];
#pragma unroll
        for (int g = 0; g < 2; g++) {
            f32x4 s[2][4] = {};
#pragma unroll
            for (int ks = 0; ks < 2; ks++) {
                bf16x8 ak[4];
#pragma unroll
                for (int n2 = 0; n2 < 4; n2++) {
                    int nt = g * 4 + n2;
                    ak[n2] = *(const bf16x8*)(Ks + (nt * 16 + l15) * KSTRIDE +
                                              ks * 32 + qd * 8);
                }
#pragma unroll
                for (int mt = 0; mt < 2; mt++)
#pragma unroll
                    for (int n2 = 0; n2 < 4; n2++)
                        s[mt][n2] = MFMA16(ak[n2], aq[mt][ks], s[mt][n2]);
            }
#pragma unroll
            for (int n2 = 0; n2 < 4; n2++) {
                int nt = g * 4 + n2;
                ushort4 mu = *(const ushort4*)(mask + b * S + kt * 128 +
                                               nt * 16 + qd * 4);
                float mv[4];
                mv[0] = fmaf(SM_MASK2, us2f(mu.x), SM_SHIFT2);
                mv[1] = fmaf(SM_MASK2, us2f(mu.y), SM_SHIFT2);
                mv[2] = fmaf(SM_MASK2, us2f(mu.z), SM_SHIFT2);
                mv[3] = fmaf(SM_MASK2, us2f(mu.w), SM_SHIFT2);
#pragma unroll
                for (int mt = 0; mt < 2; mt++)
#pragma unroll
                    for (int r = 0; r < 4; r++) {
                        float p = __builtin_amdgcn_exp2f(
                            fmaf(s[mt][n2][r], SM_SCALE2, mv[r]));
                        s[mt][n2][r] = p;
                        lacc[mt] += p;
                    }
            }
#pragma unroll
            for (int mt = 0; mt < 2; mt++)
#pragma unroll
                for (int half = 0; half < 2; half++) {
                    bf16x8 p8;
#pragma unroll
                    for (int j = 0; j < 4; j++) {
                        p8[j] = f2bs(s[mt][2 * half][j]);
                        p8[4 + j] = f2bs(s[mt][2 * half + 1][j]);
                    }
                    pb[mt][g * 2 + half] = p8;
                }
        }
#pragma unroll
        for (int c = 0; c < 4; c++) {
            bf16x8 av[4];
#pragma unroll
            for (int dt = 0; dt < 4; dt++) {
                const bf16* vb = Vs + (dt * 16 + l15) * VSTRIDE + qd * 4;
                bf16x4 lo = *(const bf16x4*)(vb + (2 * c) * 16);
                bf16x4 hi = *(const bf16x4*)(vb + (2 * c + 1) * 16);
                av[dt] = __builtin_shufflevector(lo, hi, 0, 1, 2, 3, 4, 5, 6, 7);
            }
#pragma unroll
            for (int mt = 0; mt < 2; mt++)
#pragma unroll
                for (int dt = 0; dt < 4; dt++)
                    OT[mt][dt] = MFMA16(av[dt], pb[mt][c], OT[mt][dt]);
        }
    }
#pragma unroll
    for (int mt = 0; mt < 2; mt++) {
        float rs = lacc[mt];
        rs += __shfl_xor(rs, 16);
        rs += __shfl_xor(rs, 32);
        const float inv = 1.f / rs;
        const int row = qt * 128 + wave * 32 + mt * 16 + l15;
#pragma unroll
        for (int dt = 0; dt < 4; dt++) {
            bf16x4 st;
#pragma unroll
            for (int r = 0; r < 4; r++) st[r] = f2bs(OT[mt][dt][r] * inv);
            *(bf16x4*)(ctx + baseBSD + (size_t)row * D + h * 64 + dt * 16 +
                       qd * 4) = st;
        }
    }
}

// ---------------------------------------------------------------------------
// x1 = LayerNorm(X + Y) * g + be (bf16 out; X/out may alias row-wise).
// ---------------------------------------------------------------------------
__global__ __launch_bounds__(256) void ln_add(const bf16* X,
                                              const bf16* __restrict__ Y,
                                              const bf16* __restrict__ g,
                                              const bf16* __restrict__ be,
                                              bf16* out) {
    const int tid = threadIdx.x;
    const int row = blockIdx.x;
    const size_t base = (size_t)row * 1024 + tid * 4;
    float v[4];
#pragma unroll
    for (int i = 0; i < 4; i++) v[i] = b2f(X[base + i]) + b2f(Y[base + i]);
    float s1 = 0.f, s2 = 0.f;
#pragma unroll
    for (int i = 0; i < 4; i++) {
        s1 += v[i];
        s2 += v[i] * v[i];
    }
    for (int off = 32; off; off >>= 1) {
        s1 += __shfl_xor(s1, off);
        s2 += __shfl_xor(s2, off);
    }
    __shared__ float red[8];
    const int wave = tid >> 6, lane = tid & 63;
    if (lane == 0) {
        red[wave] = s1;
        red[4 + wave] = s2;
    }
    __syncthreads();
    s1 = red[0] + red[1] + red[2] + red[3];
    s2 = red[4] + red[5] + red[6] + red[7];
    const float mu = s1 * (1.f / 1024.f);
    const float var = s2 * (1.f / 1024.f) - mu * mu;
    const float rstd = rsqrtf(var + 1e-6f);
    bf16 oh[4];
#pragma unroll
    for (int i = 0; i < 4; i++) {
        float gg = b2f(g[tid * 4 + i]);
        float bb = b2f(be[tid * 4 + i]);
        oh[i] = f2b(gg * (v[i] - mu) * rstd + bb);
    }
    *(ushort4*)(out + base) = *(ushort4*)oh;
}

// ---------------------------------------------------------------------------
// x1 = LayerNorm(X + P0 + P1) * g + be; P0/P1 fp32 split-K partials.
// ---------------------------------------------------------------------------
__global__ __launch_bounds__(256) void ln_add2f(const bf16* X,
                                                const float* __restrict__ P0,
                                                const float* __restrict__ P1,
                                                const bf16* __restrict__ g,
                                                const bf16* __restrict__ be,
                                                bf16* out) {
    const int tid = threadIdx.x;
    const int row = blockIdx.x;
    const size_t base = (size_t)row * 1024 + tid * 4;
    float4 p0 = *(const float4*)(P0 + base);
    float4 p1 = *(const float4*)(P1 + base);
    float v[4];
    v[0] = b2f(X[base + 0]) + p0.x + p1.x;
    v[1] = b2f(X[base + 1]) + p0.y + p1.y;
    v[2] = b2f(X[base + 2]) + p0.z + p1.z;
    v[3] = b2f(X[base + 3]) + p0.w + p1.w;
    float s1 = 0.f, s2 = 0.f;
#pragma unroll
    for (int i = 0; i < 4; i++) {
        s1 += v[i];
        s2 += v[i] * v[i];
    }
    for (int off = 32; off; off >>= 1) {
        s1 += __shfl_xor(s1, off);
        s2 += __shfl_xor(s2, off);
    }
    __shared__ float red[8];
    const int wave = tid >> 6, lane = tid & 63;
    if (lane == 0) {
        red[wave] = s1;
        red[4 + wave] = s2;
    }
    __syncthreads();
    s1 = red[0] + red[1] + red[2] + red[3];
    s2 = red[4] + red[5] + red[6] + red[7];
    const float mu = s1 * (1.f / 1024.f);
    const float var = s2 * (1.f / 1024.f) - mu * mu;
    const float rstd = rsqrtf(var + 1e-6f);
    bf16 oh[4];
#pragma unroll
    for (int i = 0; i < 4; i++) {
        float gg = b2f(g[tid * 4 + i]);
        float bb = b2f(be[tid * 4 + i]);
        oh[i] = f2b(gg * (v[i] - mu) * rstd + bb);
    }
    *(ushort4*)(out + base) = *(ushort4*)oh;
}

// ---------------------------------------------------------------------------
// Final LN: X bf16; Y = y2 living in d_out (fp32 if *flag else bf16);
// writes d_out in-place in the harness dtype.
// ---------------------------------------------------------------------------
__global__ __launch_bounds__(256) void ln_add_out(const bf16* __restrict__ X,
                                                  const void* Yv,
                                                  const bf16* __restrict__ g,
                                                  const bf16* __restrict__ be,
                                                  void* out,
                                                  const int* __restrict__ flag) {
    const int tid = threadIdx.x;
    const int row = blockIdx.x;
    const size_t base = (size_t)row * 1024 + tid * 4;
    const int f = *flag;
    float v[4];
    if (f) {
        float4 y = *(const float4*)((const float*)Yv + base);
        v[0] = b2f(X[base + 0]) + y.x;
        v[1] = b2f(X[base + 1]) + y.y;
        v[2] = b2f(X[base + 2]) + y.z;
        v[3] = b2f(X[base + 3]) + y.w;
    } else {
        const bf16* Yh = (const bf16*)Yv;
#pragma unroll
        for (int i = 0; i < 4; i++) v[i] = b2f(X[base + i]) + b2f(Yh[base + i]);
    }
    float s1 = 0.f, s2 = 0.f;
#pragma unroll
    for (int i = 0; i < 4; i++) {
        s1 += v[i];
        s2 += v[i] * v[i];
    }
    for (int off = 32; off; off >>= 1) {
        s1 += __shfl_xor(s1, off);
        s2 += __shfl_xor(s2, off);
    }
    __shared__ float red[8];
    const int wave = tid >> 6, lane = tid & 63;
    if (lane == 0) {
        red[wave] = s1;
        red[4 + wave] = s2;
    }
    __syncthreads();
    s1 = red[0] + red[1] + red[2] + red[3];
    s2 = red[4] + red[5] + red[6] + red[7];
    const float mu = s1 * (1.f / 1024.f);
    const float var = s2 * (1.f / 1024.f) - mu * mu;
    const float rstd = rsqrtf(var + 1e-6f);
    float o[4];
#pragma unroll
    for (int i = 0; i < 4; i++) {
        float gg = b2f(g[tid * 4 + i]);
        float bb = b2f(be[tid * 4 + i]);
        o[i] = gg * (v[i] - mu) * rstd + bb;
    }
    if (f) {
        *(float4*)((float*)out + base) = make_float4(o[0], o[1], o[2], o[3]);
    } else {
        bf16 oh[4];
#pragma unroll
        for (int i = 0; i < 4; i++) oh[i] = f2b(o[i]);
        *(ushort4*)((bf16*)out + base) = *(ushort4*)oh;
    }
}

// ---------------------------------------------------------------------------
// Final LN, split-K variant: v = X + P0 + P1 (both fp32). P0 may alias out
// (row-aligned in-place is safe). Writes harness dtype per flag.
// ---------------------------------------------------------------------------
__global__ __launch_bounds__(256) void ln_add_out2f(const bf16* __restrict__ X,
                                                    const float* P0,
                                                    const float* __restrict__ P1,
                                                    const bf16* __restrict__ g,
                                                    const bf16* __restrict__ be,
                                                    void* out,
                                                    const int* __restrict__ flag) {
    const int tid = threadIdx.x;
    const int row = blockIdx.x;
    const size_t base = (size_t)row * 1024 + tid * 4;
    const int f = *flag;
    float4 p0 = *(const float4*)(P0 + base);
    float4 p1 = *(const float4*)(P1 + base);
    float v[4];
    v[0] = b2f(X[base + 0]) + p0.x + p1.x;
    v[1] = b2f(X[base + 1]) + p0.y + p1.y;
    v[2] = b2f(X[base + 2]) + p0.z + p1.z;
    v[3] = b2f(X[base + 3]) + p0.w + p1.w;
    float s1 = 0.f, s2 = 0.f;
#pragma unroll
    for (int i = 0; i < 4; i++) {
        s1 += v[i];
        s2 += v[i] * v[i];
    }
    for (int off = 32; off; off >>= 1) {
        s1 += __shfl_xor(s1, off);
        s2 += __shfl_xor(s2, off);
    }
    __shared__ float red[8];
    const int wave = tid >> 6, lane = tid & 63;
    if (lane == 0) {
        red[wave] = s1;
        red[4 + wave] = s2;
    }
    __syncthreads();
    s1 = red[0] + red[1] + red[2] + red[3];
    s2 = red[4] + red[5] + red[6] + red[7];
    const float mu = s1 * (1.f / 1024.f);
    const float var = s2 * (1.f / 1024.f) - mu * mu;
    const float rstd = rsqrtf(var + 1e-6f);
    float o[4];
#pragma unroll
    for (int i = 0; i < 4; i++) {
        float gg = b2f(g[tid * 4 + i]);
        float bb = b2f(be[tid * 4 + i]);
        o[i] = gg * (v[i] - mu) * rstd + bb;
    }
    if (f) {
        *(float4*)((float*)out + base) = make_float4(o[0], o[1], o[2], o[3]);
    } else {
        bf16 oh[4];
#pragma unroll
        for (int i = 0; i < 4; i++) oh[i] = f2b(o[i]);
        *(ushort4*)((bf16*)out + base) = *(ushort4*)oh;
    }
}

// ---------------------------------------------------------------------------
extern "C" void kernel_launch(void* const* d_in, const int* in_sizes, int n_in,
                              void* d_out, int out_size, void* d_ws, size_t ws_size,
                              hipStream_t stream) {
    const void* x = d_in[0];
    const void* mask = d_in[1];
    const void* Wq = d_in[2];
    const void* bq = d_in[3];
    const void* Wk = d_in[4];
    const void* bk = d_in[5];
    const void* Wv = d_in[6];
    const void* bv = d_in[7];
    const void* Wo = d_in[8];
    const void* bo = d_in[9];
    const void* g1 = d_in[10];
    const void* be1 = d_in[11];
    const void* W1 = d_in[12];
    const void* bf1 = d_in[13];
    const void* W2 = d_in[14];
    const void* bf2 = d_in[15];
    const void* g2 = d_in[16];
    const void* be2 = d_in[17];

    char* ws = (char*)d_ws;
    const size_t MB = 1u << 20;
    const size_t KB = 1u << 10;
    // --- workspace base layout (high-water 88.05 MB without split) ---
    bf16* WqkvT = (bf16*)(ws + 0 * MB);  // [3072][1024] (Wq|Wk|Wv), 6 MB
    bf16* WoT = (bf16*)(ws + 6 * MB);    // 2 MB
    bf16* xc = (bf16*)(ws + 8 * MB);     // 16 MB; becomes x1 in-place (step 6)
    bf16* Qb = (bf16*)(ws + 24 * MB);    // 16 MB
    bf16* Kb = (bf16*)(ws + 40 * MB);    // 16 MB
    bf16* Vb = (bf16*)(ws + 56 * MB);    // 16 MB
    bf16* Vtb = (bf16*)(ws + 72 * MB);   // 16 MB
    char* sm = ws + 88 * MB;
    int* flag = (int*)(sm + 0);
    bf16* mask_c = (bf16*)(sm + 4 * KB);
    bf16* bqkv_c = (bf16*)(sm + 20 * KB);
    bf16* bo_c = (bf16*)(sm + 26 * KB);
    bf16* bf1_c = (bf16*)(sm + 28 * KB);
    bf16* bf2_c = (bf16*)(sm + 36 * KB);
    bf16* g1_c = (bf16*)(sm + 38 * KB);
    bf16* be1_c = (bf16*)(sm + 40 * KB);
    bf16* g2_c = (bf16*)(sm + 42 * KB);
    bf16* be2_c = (bf16*)(sm + 44 * KB);
    // aliases (stream-order safe):
    bf16* yb = Qb;                      // step 5 out (Q dead after attn)
    bf16* ctxb = Vb;                    // step 4 out (V dead after Vt)
    bf16* x1b = xc;                     // step 6: LN in-place over xc
    bf16* W1T = (bf16*)(ws + 0 * MB);   // step 6.5 (QKV/Wo weights dead), 8 MB
    bf16* W2T = (bf16*)(ws + 0 * MB);   // step 7.5 (W1T dead), 8 MB
    bf16* hb = Qb;                      // step 7: 24-88 MB (64 MB, all dead)
    // --- split-K extension (guarded): pk1 = fp32 partial at 89-121 MB ---
    float* pk1 = (float*)(ws + 89 * MB);
    float* yw0 = (float*)Qb;            // Wo partial0, fp32 32 MB over 24-56 (Q,K dead)
    const bool f32out = (out_size >= 32 * 1024 * 1024);
    // FFN2 partial0: d_out if fp32 harness, else extra ws at 121-153 MB
    float* p0f = f32out ? (float*)d_out : (float*)(ws + 121 * MB);
    const size_t need_ws = f32out ? 121 * MB + 32 * MB : 153 * MB + 32 * MB;
    const bool do_split = (ws_size >= need_ws);

    dim3 blk(256);
    dim3 blk5(512);
    // 0. dtype detect + conversions
    detect_k<<<dim3(1), blk, 0, stream>>>((const unsigned short*)x, flag);
    cvt_k<<<dim3(8192), blk, 0, stream>>>(x, xc, 8388608, flag);
    CvtBatch cb;
    cb.src[0] = mask;  cb.dst[0] = mask_c;        cb.n[0] = 8192;
    cb.src[1] = bq;    cb.dst[1] = bqkv_c;        cb.n[1] = 1024;
    cb.src[2] = bk;    cb.dst[2] = bqkv_c + 1024; cb.n[2] = 1024;
    cb.src[3] = bv;    cb.dst[3] = bqkv_c + 2048; cb.n[3] = 1024;
    cb.src[4] = bo;    cb.dst[4] = bo_c;          cb.n[4] = 1024;
    cb.src[5] = bf1;   cb.dst[5] = bf1_c;         cb.n[5] = 4096;
    cb.src[6] = bf2;   cb.dst[6] = bf2_c;         cb.n[6] = 1024;
    cb.src[7] = g1;    cb.dst[7] = g1_c;          cb.n[7] = 1024;
    cb.src[8] = be1;   cb.dst[8] = be1_c;         cb.n[8] = 1024;
    cb.src[9] = g2;    cb.dst[9] = g2_c;          cb.n[9] = 1024;
    cb.src[10] = be2;  cb.dst[10] = be2_c;        cb.n[10] = 1024;
    cvt_small_k<<<dim3(11), blk, 0, stream>>>(cb, flag);
    // 1. attention weight transposes
    transpose_k<<<dim3(16, 16, 1), blk, 0, stream>>>(Wq, WqkvT, 1024, 1024, flag);
    transpose_k<<<dim3(16, 16, 1), blk, 0, stream>>>(Wk, WqkvT + 1024 * 1024, 1024, 1024, flag);
    transpose_k<<<dim3(16, 16, 1), blk, 0, stream>>>(Wv, WqkvT + 2048 * 1024, 1024, 1024, flag);
    transpose_k<<<dim3(16, 16, 1), blk, 0, stream>>>(Wo, WoT, 1024, 1024, flag);
    // 2. fused QKV projection (N=3072, epilogue splits into Qb/Kb/Vb); 384 wgs
    gemm256<<<dim3(384), blk5, 0, stream>>>(xc, 1024, WqkvT, 1024, bqkv_c, Qb, 1024, 8192, 3072, 1024, FLAG_QKV, nullptr, nullptr);
    // 3. V -> Vt[b, d, s]
    transpose_k<<<dim3(16, 16, 8), blk, 0, stream>>>(Vb, Vtb, 1024, 1024, nullptr);
    // 4. attention -> ctx (1024 linear blocks, XCD-locality remap)
    attn_k<<<dim3(1024), blk, 0, stream>>>(Qb, Kb, Vtb, mask_c, ctxb);
    // 5+6. y = ctx @ Wo + bo ; x1 = LN(x + y)
    if (do_split) {
        // split-K x2: 256 wgs, partials fp32 (yw0 over dead Q/K, pk1 at 89 MB)
        gemm256<<<dim3(256), blk5, 0, stream>>>(ctxb, 1024, WoT, 1024, bo_c, yw0, 1024, 8192, 1024, 1024, FLAG_SPLITK, nullptr, pk1);
        ln_add2f<<<dim3(8192), blk, 0, stream>>>(xc, yw0, pk1, g1_c, be1_c, x1b);
    } else {
        gemm256<<<dim3(128), blk5, 0, stream>>>(ctxb, 1024, WoT, 1024, bo_c, yb, 1024, 8192, 1024, 1024, 0, nullptr, nullptr);
        ln_add<<<dim3(8192), blk, 0, stream>>>(xc, yb, g1_c, be1_c, x1b);
    }
    // 6.5 W1T into 0-8 MB (QKV/Wo weights dead)
    transpose_k<<<dim3(64, 16, 1), blk, 0, stream>>>(W1, W1T, 1024, 4096, flag);
    // 7. h = relu(x1 @ W1 + bf1), N=4096, hb = 24-88 MB; 512 wgs (2 rounds)
    gemm256<<<dim3(512), blk5, 0, stream>>>(x1b, 1024, W1T, 1024, bf1_c, hb, 4096, 8192, 4096, 1024, FLAG_RELU, nullptr, nullptr);
    // 7.5 W2T into 0-8 MB (W1T dead)
    transpose_k<<<dim3(16, 64, 1), blk, 0, stream>>>(W2, W2T, 4096, 1024, flag);
    // 8+9. y2 = h @ W2 + bf2 ; out = LN(x1 + y2)
    if (do_split) {
        gemm256<<<dim3(256), blk5, 0, stream>>>(hb, 4096, W2T, 4096, bf2_c, p0f, 1024, 8192, 1024, 4096, FLAG_SPLITK, nullptr, pk1);
        ln_add_out2f<<<dim3(8192), blk, 0, stream>>>(x1b, p0f, pk1, g2_c, be2_c, d_out, flag);
    } else {
        gemm256<<<dim3(128), blk5, 0, stream>>>(hb, 4096, W2T, 4096, bf2_c, d_out, 1024, 8192, 1024, 4096, FLAG_OUTF32, flag, nullptr);
        ln_add_out<<<dim3(8192), blk, 0, stream>>>(x1b, d_out, g2_c, be2_c, d_out, flag);
    }
}

// Round 8
// 532.176 us; speedup vs baseline: 1.1201x; 1.0873x over previous
//
#include <hip/hip_runtime.h>
#include <hip/hip_bf16.h>
#include <math.h>

// ---------------------------------------------------------------------------
// EncoderBlock on MI355X (gfx950). B=8, S=1024, D=1024, H=16, DH=64, F=4096.
// Round 15: (1) transpose_k vectorized to 16 B/lane global accesses on BOTH
// sides (was 2-4 B/lane scalar -- ~8x under the coalescing sweet spot across
// 7 launches); LDS tile [64][72] keeps 16B LDS writes aligned at the 8/bank
// floor. (2) attn: s_setprio(1) around QK^T and PV MFMA clusters (T5,
// measured +4-7% on multi-block attn). GEMM structure untouched (round-14
// exp2 fix + epilogue ping-pong + split-K + XCD remaps retained).
// ---------------------------------------------------------------------------

typedef __hip_bfloat16 bf16;
typedef short bf16x8 __attribute__((ext_vector_type(8)));   // MFMA A/B frag (8 bf16)
typedef short bf16x4 __attribute__((ext_vector_type(4)));   // half-frag (8 B)
typedef float f32x4 __attribute__((ext_vector_type(4)));    // MFMA C/D frag

typedef unsigned int __attribute__((address_space(1))) as1_uint;
typedef unsigned int __attribute__((address_space(3))) as3_uint;

#define MFMA16(a, b, c) __builtin_amdgcn_mfma_f32_16x16x32_bf16((a), (b), (c), 0, 0, 0)
#define FLAG_RELU 1
#define FLAG_QKV 4
#define FLAG_OUTF32 8
#define FLAG_SPLITK 16
#define KSTRIDE 68    // K-tile row stride (dh 64 + 4 pad)
#define VSTRIDE 132   // V-tile row stride (s 128 + 4 pad)
// exp2-folded softmax constants (LOG2E = 1.44269504)
#define SM_SCALE2 0.18033688f      // 0.125 * log2e
#define SM_MASK2 -1.44269504e9f    // -1e9 * log2e
#define SM_SHIFT2 -28.8539008f     // -20 * log2e

// compiler-fenced raw barrier (no implicit vmcnt(0) drain like __syncthreads)
#define BAR() do { asm volatile("" ::: "memory"); \
    __builtin_amdgcn_s_barrier(); \
    asm volatile("" ::: "memory"); } while (0)
#define WAIT_LGKM0() do { asm volatile("s_waitcnt lgkmcnt(0)" ::: "memory"); \
    __builtin_amdgcn_sched_barrier(0); } while (0)
#define WAIT_VM4() do { asm volatile("s_waitcnt vmcnt(4)" ::: "memory"); \
    __builtin_amdgcn_sched_barrier(0); } while (0)
#define WAIT_VM0() do { asm volatile("s_waitcnt vmcnt(0)" ::: "memory"); \
    __builtin_amdgcn_sched_barrier(0); } while (0)

__device__ __forceinline__ float b2f(bf16 v) { return __bfloat162float(v); }
__device__ __forceinline__ bf16 f2b(float v) { return __float2bfloat16(v); }
__device__ __forceinline__ short f2bs(float v) {
    union { bf16 h; short s; } u;
    u.h = f2b(v);
    return u.s;
}
__device__ __forceinline__ float us2f(unsigned short u) {
    return __uint_as_float(((unsigned int)u) << 16);
}

__device__ __forceinline__ void async_copy16(void* lds, const void* gp) {
    __builtin_amdgcn_global_load_lds((const as1_uint*)gp, (as3_uint*)lds, 16, 0, 0);
}

// ---------------------------------------------------------------------------
// Input dtype detector (flag=1 -> inputs are float32).
// ---------------------------------------------------------------------------
__global__ void detect_k(const unsigned short* __restrict__ xs, int* flag) {
    __shared__ int vote;
    if (threadIdx.x == 0) vote = 0;
    __syncthreads();
    int bad = 0;
    for (int i = threadIdx.x; i < 16384; i += 256) {
        int e = (xs[i] >> 7) & 0xFF;
        if (e >= 0x84) bad = 1;
    }
    if (bad) atomicOr(&vote, 1);
    __syncthreads();
    if (threadIdx.x == 0) *flag = vote;
}

// ---------------------------------------------------------------------------
// Convert large tensor to bf16.
// ---------------------------------------------------------------------------
__global__ __launch_bounds__(256) void cvt_k(const void* __restrict__ in,
                                             bf16* __restrict__ out, int n,
                                             const int* __restrict__ flag) {
    const int f = *flag;
    const int base = (blockIdx.x * 256 + threadIdx.x) * 4;
    if (f) {
        const float* p = (const float*)in;
#pragma unroll
        for (int j = 0; j < 4; j++) {
            int i = base + j;
            if (i < n) out[i] = f2b(p[i]);
        }
    } else {
        const bf16* p = (const bf16*)in;
#pragma unroll
        for (int j = 0; j < 4; j++) {
            int i = base + j;
            if (i < n) out[i] = p[i];
        }
    }
}

// ---------------------------------------------------------------------------
// Batched conversion of the 11 small tensors (one block per tensor).
// ---------------------------------------------------------------------------
struct CvtBatch {
    const void* src[11];
    bf16* dst[11];
    int n[11];
};
__global__ __launch_bounds__(256) void cvt_small_k(CvtBatch cb,
                                                   const int* __restrict__ flag) {
    const int f = *flag;
    const int seg = blockIdx.x;
    const int n = cb.n[seg];
    const void* in = cb.src[seg];
    bf16* out = cb.dst[seg];
    if (f) {
        const float* p = (const float*)in;
        for (int i = threadIdx.x; i < n; i += 256) out[i] = f2b(p[i]);
    } else {
        const bf16* p = (const bf16*)in;
        for (int i = threadIdx.x; i < n; i += 256) out[i] = p[i];
    }
}

// ---------------------------------------------------------------------------
// Transpose: out[z][C][R] = in[z][R][C]. flag-aware read (nullptr = bf16).
// 16 B/lane global accesses both sides. LDS tile [64][72]: 144 B row stride
// keeps every 16 B LDS write aligned; b128 writes land at the 8/bank floor.
// Requires R%64==0, C%64==0 (true for all call sites).
// ---------------------------------------------------------------------------
__global__ __launch_bounds__(256) void transpose_k(const void* __restrict__ in,
                                                   bf16* __restrict__ out,
                                                   int R, int C,
                                                   const int* __restrict__ flag) {
    __shared__ __align__(16) bf16 tile[64][72];
    const int f = flag ? *flag : 0;
    const int tid = threadIdx.x;
    const size_t zoff = (size_t)blockIdx.z * R * C;
    const int tr = blockIdx.y * 64, tc = blockIdx.x * 64;
    // load: 2 units/thread, each 8 consecutive cols of one row (16 B bf16)
#pragma unroll
    for (int it = 0; it < 2; ++it) {
        const int u = it * 256 + tid;
        const int r = u >> 3, c8 = (u & 7) * 8;
        const size_t g = zoff + (size_t)(tr + r) * C + tc + c8;
        bf16x8 v;
        if (f) {
            const float* p = (const float*)in + g;
            float4 a = *(const float4*)p;
            float4 b = *(const float4*)(p + 4);
            v[0] = f2bs(a.x); v[1] = f2bs(a.y); v[2] = f2bs(a.z); v[3] = f2bs(a.w);
            v[4] = f2bs(b.x); v[5] = f2bs(b.y); v[6] = f2bs(b.z); v[7] = f2bs(b.w);
        } else {
            v = *(const bf16x8*)((const bf16*)in + g);
        }
        *(bf16x8*)&tile[r][c8] = v;
    }
    __syncthreads();
    // store: 2 units/thread, each 8 consecutive out-cols (= in-rows) of one
    // out-row (= in-col) -> 16 B stores, 8 lanes per 128 B segment
#pragma unroll
    for (int it = 0; it < 2; ++it) {
        const int u = it * 256 + tid;
        const int cr = u >> 3, r8 = (u & 7) * 8;
        bf16x8 v;
#pragma unroll
        for (int j = 0; j < 8; ++j) v[j] = *(const short*)&tile[r8 + j][cr];
        *(bf16x8*)(out + zoff + (size_t)(tc + cr) * R + tr + r8) = v;
    }
}

// ---------------------------------------------------------------------------
// 256x256 8-phase GEMM: C[M,N](ldc) = A[M,K](lda) @ Bt[N,K](ldb)^T + bias.
// 512 threads = 8 waves (2M x 4N), per-wave 128x64 output (acc[8][4]), BK=64.
// T2 swizzle + T3/T4 counted-vmcnt pipeline + T5 setprio (see round 8/9).
// FLAG_SPLITK: grid = 2*(M/256)*(N/256); kpart = swz&1 selects K-half;
// fp32 partial to Cv (kpart0, +bias) / Cv2 (kpart1, no bias). No RELU.
// Epilogue: wave-private scratch ping-pongs between dead As/Bs (no per-pass
// lgkm drain); bf16 path stores 16 B/lane. Requires M%256==0, N%256==0,
// K%64==0 (K%128==0 if split), nwg%8==0.
// ---------------------------------------------------------------------------
__global__ __launch_bounds__(512, 2) void gemm256(const bf16* __restrict__ A, int lda,
                                                  const bf16* __restrict__ Bt, int ldb,
                                                  const bf16* __restrict__ bias,
                                                  void* __restrict__ Cv, int ldc,
                                                  int M, int N, int K, int flags,
                                                  const int* __restrict__ dtf,
                                                  void* __restrict__ Cv2) {
    __shared__ __align__(16) bf16 As[2][256 * 64];   // 64 KiB
    __shared__ __align__(16) bf16 Bs[2][256 * 64];   // 64 KiB
    const int tid = threadIdx.x;
    const int wave = tid >> 6, lane = tid & 63;
    const int qd = lane >> 4, l15 = lane & 15;
    const int wm = wave >> 2, wn = wave & 3;         // 2 x 4 wave grid

    // XCD-aware block swizzle (nwg is a multiple of 8 for all our shapes)
    const int NB = N >> 8;
    const int cpx = gridDim.x >> 3;
    const int swz = ((int)blockIdx.x & 7) * cpx + ((int)blockIdx.x >> 3);
    const int splitk = flags & FLAG_SPLITK;
    const int kpart = splitk ? (swz & 1) : 0;
    const int tileIdx = splitk ? (swz >> 1) : swz;
    const int bn = tileIdx % NB, bm = tileIdx / NB;
    const int Keff = splitk ? (K >> 1) : K;
    const int koff = kpart ? Keff : 0;

    // ---- staging: pre-swizzled global source, linear LDS dest ----
    const int srow = tid >> 3;                        // 0..63 (row in sweep)
    const int schunk = (tid & 7) ^ (srow & 7);        // XOR-swizzled k-chunk
    const bf16* gA = A + (size_t)(bm * 256 + srow) * lda + koff + schunk * 8;
    const bf16* gB = Bt + (size_t)(bn * 256 + srow) * ldb + koff + schunk * 8;
    char* lA = (char*)As + wave * 1024;
    char* lB = (char*)Bs + wave * 1024;

    auto stA = [&](int d, int h, int tt) {
        const bf16* g = gA + (size_t)(h * 128) * lda + tt * 64;
        char* l = lA + d * 32768 + h * 16384;
        async_copy16(l, g);
        async_copy16(l + 8192, g + (size_t)64 * lda);
    };
    auto stB = [&](int d, int h, int tt) {
        const bf16* g = gB + (size_t)(h * 128) * ldb + tt * 64;
        char* l = lB + d * 32768 + h * 16384;
        async_copy16(l, g);
        async_copy16(l + 8192, g + (size_t)64 * ldb);
    };

    // ---- swizzled ds_read offsets (bytes). row&7 == l15&7 for all frags ----
    const int sx = l15 & 7;
    const char* pA = (const char*)As + (wm * 128 + l15) * 128;
    const char* pB = (const char*)Bs + (wn * 64 + l15) * 128;
    const int c0 = ((0 + qd) ^ sx) * 16;   // kk=0: global chunk qd
    const int c1 = ((4 + qd) ^ sx) * 16;   // kk=1: global chunk 4+qd

    f32x4 acc[8][4] = {};
    bf16x8 af[4][2], bfr[4][2];
    const int nt = Keff >> 6;

    // ---- prologue: tile 0 fully + B0/A0 of tile 1 in flight ----
    stA(0, 0, 0); stA(0, 1, 0); stB(0, 0, 0); stB(0, 1, 0);
    if (nt > 1) {
        stB(1, 0, 1); stA(1, 0, 1);
        WAIT_VM4();
    } else {
        WAIT_VM0();
    }
    BAR();

#pragma unroll 2
    for (int t = 0; t < nt; ++t) {
        const int d = t & 1, dn = d ^ 1;
        const int db = d * 32768;
        // ---------- phase 1: quadrant (m0-3, n0-1); 12 ds_reads ----------
#pragma unroll
        for (int m = 0; m < 4; ++m) {
            af[m][0] = *(const bf16x8*)(pA + db + m * 2048 + c0);
            af[m][1] = *(const bf16x8*)(pA + db + m * 2048 + c1);
        }
#pragma unroll
        for (int n = 0; n < 2; ++n) {
            bfr[n][0] = *(const bf16x8*)(pB + db + n * 2048 + c0);
            bfr[n][1] = *(const bf16x8*)(pB + db + n * 2048 + c1);
        }
        if (t + 1 < nt) stB(dn, 1, t + 1);
        BAR();
        WAIT_LGKM0();
        __builtin_amdgcn_s_setprio(1);
#pragma unroll
        for (int kk = 0; kk < 2; ++kk)
#pragma unroll
            for (int m = 0; m < 4; ++m)
#pragma unroll
                for (int n = 0; n < 2; ++n)
                    acc[m][n] = MFMA16(af[m][kk], bfr[n][kk], acc[m][n]);
        __builtin_amdgcn_s_setprio(0);
        BAR();
        // ---------- phase 2: quadrant (m0-3, n2-3); 4 ds_reads ----------
#pragma unroll
        for (int n = 0; n < 2; ++n) {
            bfr[2 + n][0] = *(const bf16x8*)(pB + db + (2 + n) * 2048 + c0);
            bfr[2 + n][1] = *(const bf16x8*)(pB + db + (2 + n) * 2048 + c1);
        }
        if (t + 1 < nt) stA(dn, 1, t + 1);
        BAR();
        WAIT_LGKM0();
        __builtin_amdgcn_s_setprio(1);
#pragma unroll
        for (int kk = 0; kk < 2; ++kk)
#pragma unroll
            for (int m = 0; m < 4; ++m)
#pragma unroll
                for (int n = 0; n < 2; ++n)
                    acc[m][2 + n] = MFMA16(af[m][kk], bfr[2 + n][kk], acc[m][2 + n]);
        __builtin_amdgcn_s_setprio(0);
        BAR();
        // ---------- phase 3: quadrant (m4-7, n0-1); 8 ds_reads ----------
#pragma unroll
        for (int m = 0; m < 4; ++m) {
            af[m][0] = *(const bf16x8*)(pA + db + (4 + m) * 2048 + c0);
            af[m][1] = *(const bf16x8*)(pA + db + (4 + m) * 2048 + c1);
        }
        if (t + 2 < nt) stB(d, 0, t + 2);
        BAR();
        WAIT_LGKM0();
        __builtin_amdgcn_s_setprio(1);
#pragma unroll
        for (int kk = 0; kk < 2; ++kk)
#pragma unroll
            for (int m = 0; m < 4; ++m)
#pragma unroll
                for (int n = 0; n < 2; ++n)
                    acc[4 + m][n] = MFMA16(af[m][kk], bfr[n][kk], acc[4 + m][n]);
        __builtin_amdgcn_s_setprio(0);
        BAR();
        // ---------- phase 4: quadrant (m4-7, n2-3); no ds_reads ----------
        if (t + 2 < nt) stA(d, 0, t + 2);
        BAR();
        __builtin_amdgcn_s_setprio(1);
#pragma unroll
        for (int kk = 0; kk < 2; ++kk)
#pragma unroll
            for (int m = 0; m < 4; ++m)
#pragma unroll
                for (int n = 0; n < 2; ++n)
                    acc[4 + m][2 + n] = MFMA16(af[m][kk], bfr[2 + n][kk], acc[4 + m][2 + n]);
        __builtin_amdgcn_s_setprio(0);
        // counted wait: everything tile t+1 needs has landed; only the
        // newest 4 loads (B0/A0 of tile t+2) may stay in flight.
        if (t + 2 < nt) {
            WAIT_VM4();
        } else {
            WAIT_VM0();
        }
        BAR();
    }

    // ---- epilogue: ping-pong wave-private LDS bounce -> wide stores ----
    const int of32 = (flags & FLAG_OUTF32) ? *dtf : 0;
    bf16* C = (bf16*)Cv;
    float* Cf = (float*)(kpart ? Cv2 : Cv);
    float* ep0 = (float*)((char*)As + wave * 4352);
    float* ep1 = (float*)((char*)Bs + wave * 4352);
    const bool f32path = (splitk || of32);
#pragma unroll
    for (int p = 0; p < 8; ++p) {
        float* ep = (p & 1) ? ep1 : ep0;
#pragma unroll
        for (int n = 0; n < 4; ++n)
#pragma unroll
            for (int r = 0; r < 4; ++r)
                ep[(qd * 4 + r) * 68 + n * 16 + l15] = acc[p][n][r];
        WAIT_LGKM0();
        if (f32path) {
#pragma unroll
            for (int it = 0; it < 4; ++it) {
                const int idx = it * 64 + lane;
                const int row = idx >> 4;            // 0..15
                const int colc = (idx & 15) * 4;     // 0..60, step 4
                f32x4 v = *(const f32x4*)(ep + row * 68 + colc);
                const int gcol = bn * 256 + wn * 64 + colc;
                const bf16x4 bb = *(const bf16x4*)(bias + gcol);
                const int grow = bm * 256 + wm * 128 + p * 16 + row;
#pragma unroll
                for (int j = 0; j < 4; ++j) {
                    float bvj = (kpart == 0) ? us2f((unsigned short)bb[j]) : 0.f;
                    float vv = v[j] + bvj;
                    if (flags & FLAG_RELU) vv = fmaxf(vv, 0.f);
                    v[j] = vv;
                }
                *(f32x4*)(Cf + (size_t)grow * ldc + gcol) = v;
            }
        } else {
            // bf16 path: 2 iters, 8 cols/lane, 16-B stores
#pragma unroll
            for (int it = 0; it < 2; ++it) {
                const int unit = it * 64 + lane;
                const int row = unit >> 3;           // 0..15
                const int c8 = (unit & 7) * 8;       // 0..56, step 8
                f32x4 v0 = *(const f32x4*)(ep + row * 68 + c8);
                f32x4 v1 = *(const f32x4*)(ep + row * 68 + c8 + 4);
                const int gcol = bn * 256 + wn * 64 + c8;
                const bf16x8 bb = *(const bf16x8*)(bias + gcol);
                const int grow = bm * 256 + wm * 128 + p * 16 + row;
                bf16x8 h;
#pragma unroll
                for (int j = 0; j < 4; ++j) {
                    float a0 = v0[j] + us2f((unsigned short)bb[j]);
                    float a1 = v1[j] + us2f((unsigned short)bb[4 + j]);
                    if (flags & FLAG_RELU) {
                        a0 = fmaxf(a0, 0.f);
                        a1 = fmaxf(a1, 0.f);
                    }
                    h[j] = f2bs(a0);
                    h[4 + j] = f2bs(a1);
                }
                // QKV: an 8-col chunk never straddles a 1024-col boundary
                const size_t cbase = (flags & FLAG_QKV)
                    ? (size_t)(gcol >> 10) * (8192u * 1024u) + (gcol & 1023)
                    : (size_t)gcol;
                *(bf16x8*)(C + (size_t)grow * ldc + cbase) = h;
            }
        }
    }
}

// ---------------------------------------------------------------------------
// Flash attention, S^T formulation. Grid: 1024 linear blocks, 256 threads.
// XCD-locality remap: lin&7 = XCD chunk -> all 8 qt-blocks of one (b,h) on
// one XCD; its 16 (b,h) pairs x 256KB K/V = 4MB = the XCD L2.
// Softmax: one v_exp_f32 per probability. T5 setprio around MFMA clusters.
// ---------------------------------------------------------------------------
__global__ __launch_bounds__(256) void attn_k(const bf16* __restrict__ Q,
                                              const bf16* __restrict__ Kc,
                                              const bf16* __restrict__ Vt,
                                              const bf16* __restrict__ mask,
                                              bf16* __restrict__ ctx) {
    const int S = 1024, D = 1024;
    __shared__ __align__(16) bf16 Ks[128 * KSTRIDE];  // 17.0 KB
    __shared__ __align__(16) bf16 Vs[64 * VSTRIDE];   // 16.5 KB
    const int tid = threadIdx.x, wave = tid >> 6, lane = tid & 63;
    const int qd = lane >> 4, l15 = lane & 15;
    // XCD-locality decomposition: hardware XCD = blockIdx.x % 8 (round-robin)
    const int lin = blockIdx.x;
    const int xcd = lin & 7;
    const int sub = lin >> 3;              // 0..127
    const int bh = xcd * 16 + (sub >> 3);  // 0..127, 16 (b,h) pairs per XCD
    const int qt = sub & 7;
    const int h = bh & 15, b = bh >> 4;
    const size_t baseBSD = (size_t)b * S * D;

    const bf16* gK[4]; bf16* sK[4];
    const bf16* gV[4]; bf16* sV[4];
#pragma unroll
    for (int i = 0; i < 4; i++) {
        int t = tid + i * 256;
        gK[i] = Kc + baseBSD + (size_t)(t >> 3) * D + h * 64 + (t & 7) * 8;
        sK[i] = Ks + (t >> 3) * KSTRIDE + (t & 7) * 8;
        gV[i] = Vt + ((size_t)b * D + h * 64 + (t >> 4)) * S + (t & 15) * 8;
        sV[i] = Vs + (t >> 4) * VSTRIDE + (t & 15) * 8;
    }

    bf16x8 aq[2][2];
#pragma unroll
    for (int mt = 0; mt < 2; mt++)
#pragma unroll
        for (int ks = 0; ks < 2; ks++) {
            int row = qt * 128 + wave * 32 + mt * 16 + l15;
            int col = h * 64 + ks * 32 + qd * 8;
            aq[mt][ks] = *(const bf16x8*)(Q + baseBSD + (size_t)row * D + col);
        }

    bf16x8 kreg[4], vreg[4];
#pragma unroll
    for (int i = 0; i < 4; i++) {
        kreg[i] = *(const bf16x8*)(gK[i]);
        vreg[i] = *(const bf16x8*)(gV[i]);
    }

    f32x4 OT[2][4] = {};
    float lacc[2] = {0.f, 0.f};

    for (int kt = 0; kt < 8; kt++) {
        __syncthreads();
#pragma unroll
        for (int i = 0; i < 4; i++) {
            *(bf16x8*)sK[i] = kreg[i];
            *(bf16x8*)sV[i] = vreg[i];
        }
        __syncthreads();
        const int ktn = (kt < 7) ? kt + 1 : 7;
#pragma unroll
        for (int i = 0; i < 4; i++) {
            kreg[i] = *(const bf16x8*)(gK[i] + (size_t)ktn * 128 * D);
            vreg[i] = *(const bf16x8*)(gV[i] + ktn * 128);
        }
        bf16x8 pb[2][4];
#pragma unroll
        for (int g = 0; g < 2; g++) {
            f32x4 s[2][4] = {};
#pragma unroll
            for (int ks = 0; ks < 2; ks++) {
                bf16x8 ak[4];
#pragma unroll
                for (int n2 = 0; n2 < 4; n2++) {
                    int nt = g * 4 + n2;
                    ak[n2] = *(const bf16x8*)(Ks + (nt * 16 + l15) * KSTRIDE +
                                              ks * 32 + qd * 8);
                }
                __builtin_amdgcn_s_setprio(1);
#pragma unroll
                for (int mt = 0; mt < 2; mt++)
#pragma unroll
                    for (int n2 = 0; n2 < 4; n2++)
                        s[mt][n2] = MFMA16(ak[n2], aq[mt][ks], s[mt][n2]);
                __builtin_amdgcn_s_setprio(0);
            }
#pragma unroll
            for (int n2 = 0; n2 < 4; n2++) {
                int nt = g * 4 + n2;
                ushort4 mu = *(const ushort4*)(mask + b * S + kt * 128 +
                                               nt * 16 + qd * 4);
                float mv[4];
                mv[0] = fmaf(SM_MASK2, us2f(mu.x), SM_SHIFT2);
                mv[1] = fmaf(SM_MASK2, us2f(mu.y), SM_SHIFT2);
                mv[2] = fmaf(SM_MASK2, us2f(mu.z), SM_SHIFT2);
                mv[3] = fmaf(SM_MASK2, us2f(mu.w), SM_SHIFT2);
#pragma unroll
                for (int mt = 0; mt < 2; mt++)
#pragma unroll
                    for (int r = 0; r < 4; r++) {
                        float p = __builtin_amdgcn_exp2f(
                            fmaf(s[mt][n2][r], SM_SCALE2, mv[r]));
                        s[mt][n2][r] = p;
                        lacc[mt] += p;
                    }
            }
#pragma unroll
            for (int mt = 0; mt < 2; mt++)
#pragma unroll
                for (int half = 0; half < 2; half++) {
                    bf16x8 p8;
#pragma unroll
                    for (int j = 0; j < 4; j++) {
                        p8[j] = f2bs(s[mt][2 * half][j]);
                        p8[4 + j] = f2bs(s[mt][2 * half + 1][j]);
                    }
                    pb[mt][g * 2 + half] = p8;
                }
        }
#pragma unroll
        for (int c = 0; c < 4; c++) {
            bf16x8 av[4];
#pragma unroll
            for (int dt = 0; dt < 4; dt++) {
                const bf16* vb = Vs + (dt * 16 + l15) * VSTRIDE + qd * 4;
                bf16x4 lo = *(const bf16x4*)(vb + (2 * c) * 16);
                bf16x4 hi = *(const bf16x4*)(vb + (2 * c + 1) * 16);
                av[dt] = __builtin_shufflevector(lo, hi, 0, 1, 2, 3, 4, 5, 6, 7);
            }
            __builtin_amdgcn_s_setprio(1);
#pragma unroll
            for (int mt = 0; mt < 2; mt++)
#pragma unroll
                for (int dt = 0; dt < 4; dt++)
                    OT[mt][dt] = MFMA16(av[dt], pb[mt][c], OT[mt][dt]);
            __builtin_amdgcn_s_setprio(0);
        }
    }
#pragma unroll
    for (int mt = 0; mt < 2; mt++) {
        float rs = lacc[mt];
        rs += __shfl_xor(rs, 16);
        rs += __shfl_xor(rs, 32);
        const float inv = 1.f / rs;
        const int row = qt * 128 + wave * 32 + mt * 16 + l15;
#pragma unroll
        for (int dt = 0; dt < 4; dt++) {
            bf16x4 st;
#pragma unroll
            for (int r = 0; r < 4; r++) st[r] = f2bs(OT[mt][dt][r] * inv);
            *(bf16x4*)(ctx + baseBSD + (size_t)row * D + h * 64 + dt * 16 +
                       qd * 4) = st;
        }
    }
}

// ---------------------------------------------------------------------------
// x1 = LayerNorm(X + Y) * g + be (bf16 out; X/out may alias row-wise).
// ---------------------------------------------------------------------------
__global__ __launch_bounds__(256) void ln_add(const bf16* X,
                                              const bf16* __restrict__ Y,
                                              const bf16* __restrict__ g,
                                              const bf16* __restrict__ be,
                                              bf16* out) {
    const int tid = threadIdx.x;
    const int row = blockIdx.x;
    const size_t base = (size_t)row * 1024 + tid * 4;
    float v[4];
#pragma unroll
    for (int i = 0; i < 4; i++) v[i] = b2f(X[base + i]) + b2f(Y[base + i]);
    float s1 = 0.f, s2 = 0.f;
#pragma unroll
    for (int i = 0; i < 4; i++) {
        s1 += v[i];
        s2 += v[i] * v[i];
    }
    for (int off = 32; off; off >>= 1) {
        s1 += __shfl_xor(s1, off);
        s2 += __shfl_xor(s2, off);
    }
    __shared__ float red[8];
    const int wave = tid >> 6, lane = tid & 63;
    if (lane == 0) {
        red[wave] = s1;
        red[4 + wave] = s2;
    }
    __syncthreads();
    s1 = red[0] + red[1] + red[2] + red[3];
    s2 = red[4] + red[5] + red[6] + red[7];
    const float mu = s1 * (1.f / 1024.f);
    const float var = s2 * (1.f / 1024.f) - mu * mu;
    const float rstd = rsqrtf(var + 1e-6f);
    bf16 oh[4];
#pragma unroll
    for (int i = 0; i < 4; i++) {
        float gg = b2f(g[tid * 4 + i]);
        float bb = b2f(be[tid * 4 + i]);
        oh[i] = f2b(gg * (v[i] - mu) * rstd + bb);
    }
    *(ushort4*)(out + base) = *(ushort4*)oh;
}

// ---------------------------------------------------------------------------
// x1 = LayerNorm(X + P0 + P1) * g + be; P0/P1 fp32 split-K partials.
// ---------------------------------------------------------------------------
__global__ __launch_bounds__(256) void ln_add2f(const bf16* X,
                                                const float* __restrict__ P0,
                                                const float* __restrict__ P1,
                                                const bf16* __restrict__ g,
                                                const bf16* __restrict__ be,
                                                bf16* out) {
    const int tid = threadIdx.x;
    const int row = blockIdx.x;
    const size_t base = (size_t)row * 1024 + tid * 4;
    float4 p0 = *(const float4*)(P0 + base);
    float4 p1 = *(const float4*)(P1 + base);
    float v[4];
    v[0] = b2f(X[base + 0]) + p0.x + p1.x;
    v[1] = b2f(X[base + 1]) + p0.y + p1.y;
    v[2] = b2f(X[base + 2]) + p0.z + p1.z;
    v[3] = b2f(X[base + 3]) + p0.w + p1.w;
    float s1 = 0.f, s2 = 0.f;
#pragma unroll
    for (int i = 0; i < 4; i++) {
        s1 += v[i];
        s2 += v[i] * v[i];
    }
    for (int off = 32; off; off >>= 1) {
        s1 += __shfl_xor(s1, off);
        s2 += __shfl_xor(s2, off);
    }
    __shared__ float red[8];
    const int wave = tid >> 6, lane = tid & 63;
    if (lane == 0) {
        red[wave] = s1;
        red[4 + wave] = s2;
    }
    __syncthreads();
    s1 = red[0] + red[1] + red[2] + red[3];
    s2 = red[4] + red[5] + red[6] + red[7];
    const float mu = s1 * (1.f / 1024.f);
    const float var = s2 * (1.f / 1024.f) - mu * mu;
    const float rstd = rsqrtf(var + 1e-6f);
    bf16 oh[4];
#pragma unroll
    for (int i = 0; i < 4; i++) {
        float gg = b2f(g[tid * 4 + i]);
        float bb = b2f(be[tid * 4 + i]);
        oh[i] = f2b(gg * (v[i] - mu) * rstd + bb);
    }
    *(ushort4*)(out + base) = *(ushort4*)oh;
}

// ---------------------------------------------------------------------------
// Final LN: X bf16; Y = y2 living in d_out (fp32 if *flag else bf16);
// writes d_out in-place in the harness dtype.
// ---------------------------------------------------------------------------
__global__ __launch_bounds__(256) void ln_add_out(const bf16* __restrict__ X,
                                                  const void* Yv,
                                                  const bf16* __restrict__ g,
                                                  const bf16* __restrict__ be,
                                                  void* out,
                                                  const int* __restrict__ flag) {
    const int tid = threadIdx.x;
    const int row = blockIdx.x;
    const size_t base = (size_t)row * 1024 + tid * 4;
    const int f = *flag;
    float v[4];
    if (f) {
        float4 y = *(const float4*)((const float*)Yv + base);
        v[0] = b2f(X[base + 0]) + y.x;
        v[1] = b2f(X[base + 1]) + y.y;
        v[2] = b2f(X[base + 2]) + y.z;
        v[3] = b2f(X[base + 3]) + y.w;
    } else {
        const bf16* Yh = (const bf16*)Yv;
#pragma unroll
        for (int i = 0; i < 4; i++) v[i] = b2f(X[base + i]) + b2f(Yh[base + i]);
    }
    float s1 = 0.f, s2 = 0.f;
#pragma unroll
    for (int i = 0; i < 4; i++) {
        s1 += v[i];
        s2 += v[i] * v[i];
    }
    for (int off = 32; off; off >>= 1) {
        s1 += __shfl_xor(s1, off);
        s2 += __shfl_xor(s2, off);
    }
    __shared__ float red[8];
    const int wave = tid >> 6, lane = tid & 63;
    if (lane == 0) {
        red[wave] = s1;
        red[4 + wave] = s2;
    }
    __syncthreads();
    s1 = red[0] + red[1] + red[2] + red[3];
    s2 = red[4] + red[5] + red[6] + red[7];
    const float mu = s1 * (1.f / 1024.f);
    const float var = s2 * (1.f / 1024.f) - mu * mu;
    const float rstd = rsqrtf(var + 1e-6f);
    float o[4];
#pragma unroll
    for (int i = 0; i < 4; i++) {
        float gg = b2f(g[tid * 4 + i]);
        float bb = b2f(be[tid * 4 + i]);
        o[i] = gg * (v[i] - mu) * rstd + bb;
    }
    if (f) {
        *(float4*)((float*)out + base) = make_float4(o[0], o[1], o[2], o[3]);
    } else {
        bf16 oh[4];
#pragma unroll
        for (int i = 0; i < 4; i++) oh[i] = f2b(o[i]);
        *(ushort4*)((bf16*)out + base) = *(ushort4*)oh;
    }
}

// ---------------------------------------------------------------------------
// Final LN, split-K variant: v = X + P0 + P1 (both fp32). P0 may alias out
// (row-aligned in-place is safe). Writes harness dtype per flag.
// ---------------------------------------------------------------------------
__global__ __launch_bounds__(256) void ln_add_out2f(const bf16* __restrict__ X,
                                                    const float* P0,
                                                    const float* __restrict__ P1,
                                                    const bf16* __restrict__ g,
                                                    const bf16* __restrict__ be,
                                                    void* out,
                                                    const int* __restrict__ flag) {
    const int tid = threadIdx.x;
    const int row = blockIdx.x;
    const size_t base = (size_t)row * 1024 + tid * 4;
    const int f = *flag;
    float4 p0 = *(const float4*)(P0 + base);
    float4 p1 = *(const float4*)(P1 + base);
    float v[4];
    v[0] = b2f(X[base + 0]) + p0.x + p1.x;
    v[1] = b2f(X[base + 1]) + p0.y + p1.y;
    v[2] = b2f(X[base + 2]) + p0.z + p1.z;
    v[3] = b2f(X[base + 3]) + p0.w + p1.w;
    float s1 = 0.f, s2 = 0.f;
#pragma unroll
    for (int i = 0; i < 4; i++) {
        s1 += v[i];
        s2 += v[i] * v[i];
    }
    for (int off = 32; off; off >>= 1) {
        s1 += __shfl_xor(s1, off);
        s2 += __shfl_xor(s2, off);
    }
    __shared__ float red[8];
    const int wave = tid >> 6, lane = tid & 63;
    if (lane == 0) {
        red[wave] = s1;
        red[4 + wave] = s2;
    }
    __syncthreads();
    s1 = red[0] + red[1] + red[2] + red[3];
    s2 = red[4] + red[5] + red[6] + red[7];
    const float mu = s1 * (1.f / 1024.f);
    const float var = s2 * (1.f / 1024.f) - mu * mu;
    const float rstd = rsqrtf(var + 1e-6f);
    float o[4];
#pragma unroll
    for (int i = 0; i < 4; i++) {
        float gg = b2f(g[tid * 4 + i]);
        float bb = b2f(be[tid * 4 + i]);
        o[i] = gg * (v[i] - mu) * rstd + bb;
    }
    if (f) {
        *(float4*)((float*)out + base) = make_float4(o[0], o[1], o[2], o[3]);
    } else {
        bf16 oh[4];
#pragma unroll
        for (int i = 0; i < 4; i++) oh[i] = f2b(o[i]);
        *(ushort4*)((bf16*)out + base) = *(ushort4*)oh;
    }
}

// ---------------------------------------------------------------------------
extern "C" void kernel_launch(void* const* d_in, const int* in_sizes, int n_in,
                              void* d_out, int out_size, void* d_ws, size_t ws_size,
                              hipStream_t stream) {
    const void* x = d_in[0];
    const void* mask = d_in[1];
    const void* Wq = d_in[2];
    const void* bq = d_in[3];
    const void* Wk = d_in[4];
    const void* bk = d_in[5];
    const void* Wv = d_in[6];
    const void* bv = d_in[7];
    const void* Wo = d_in[8];
    const void* bo = d_in[9];
    const void* g1 = d_in[10];
    const void* be1 = d_in[11];
    const void* W1 = d_in[12];
    const void* bf1 = d_in[13];
    const void* W2 = d_in[14];
    const void* bf2 = d_in[15];
    const void* g2 = d_in[16];
    const void* be2 = d_in[17];

    char* ws = (char*)d_ws;
    const size_t MB = 1u << 20;
    const size_t KB = 1u << 10;
    // --- workspace base layout (high-water 88.05 MB without split) ---
    bf16* WqkvT = (bf16*)(ws + 0 * MB);  // [3072][1024] (Wq|Wk|Wv), 6 MB
    bf16* WoT = (bf16*)(ws + 6 * MB);    // 2 MB
    bf16* xc = (bf16*)(ws + 8 * MB);     // 16 MB; becomes x1 in-place (step 6)
    bf16* Qb = (bf16*)(ws + 24 * MB);    // 16 MB
    bf16* Kb = (bf16*)(ws + 40 * MB);    // 16 MB
    bf16* Vb = (bf16*)(ws + 56 * MB);    // 16 MB
    bf16* Vtb = (bf16*)(ws + 72 * MB);   // 16 MB
    char* sm = ws + 88 * MB;
    int* flag = (int*)(sm + 0);
    bf16* mask_c = (bf16*)(sm + 4 * KB);
    bf16* bqkv_c = (bf16*)(sm + 20 * KB);
    bf16* bo_c = (bf16*)(sm + 26 * KB);
    bf16* bf1_c = (bf16*)(sm + 28 * KB);
    bf16* bf2_c = (bf16*)(sm + 36 * KB);
    bf16* g1_c = (bf16*)(sm + 38 * KB);
    bf16* be1_c = (bf16*)(sm + 40 * KB);
    bf16* g2_c = (bf16*)(sm + 42 * KB);
    bf16* be2_c = (bf16*)(sm + 44 * KB);
    // aliases (stream-order safe):
    bf16* yb = Qb;                      // step 5 out (Q dead after attn)
    bf16* ctxb = Vb;                    // step 4 out (V dead after Vt)
    bf16* x1b = xc;                     // step 6: LN in-place over xc
    bf16* W1T = (bf16*)(ws + 0 * MB);   // step 6.5 (QKV/Wo weights dead), 8 MB
    bf16* W2T = (bf16*)(ws + 0 * MB);   // step 7.5 (W1T dead), 8 MB
    bf16* hb = Qb;                      // step 7: 24-88 MB (64 MB, all dead)
    // --- split-K extension (guarded): pk1 = fp32 partial at 89-121 MB ---
    float* pk1 = (float*)(ws + 89 * MB);
    float* yw0 = (float*)Qb;            // Wo partial0, fp32 32 MB over 24-56 (Q,K dead)
    const bool f32out = (out_size >= 32 * 1024 * 1024);
    // FFN2 partial0: d_out if fp32 harness, else extra ws at 121-153 MB
    float* p0f = f32out ? (float*)d_out : (float*)(ws + 121 * MB);
    const size_t need_ws = f32out ? 121 * MB + 32 * MB : 153 * MB + 32 * MB;
    const bool do_split = (ws_size >= need_ws);

    dim3 blk(256);
    dim3 blk5(512);
    // 0. dtype detect + conversions
    detect_k<<<dim3(1), blk, 0, stream>>>((const unsigned short*)x, flag);
    cvt_k<<<dim3(8192), blk, 0, stream>>>(x, xc, 8388608, flag);
    CvtBatch cb;
    cb.src[0] = mask;  cb.dst[0] = mask_c;        cb.n[0] = 8192;
    cb.src[1] = bq;    cb.dst[1] = bqkv_c;        cb.n[1] = 1024;
    cb.src[2] = bk;    cb.dst[2] = bqkv_c + 1024; cb.n[2] = 1024;
    cb.src[3] = bv;    cb.dst[3] = bqkv_c + 2048; cb.n[3] = 1024;
    cb.src[4] = bo;    cb.dst[4] = bo_c;          cb.n[4] = 1024;
    cb.src[5] = bf1;   cb.dst[5] = bf1_c;         cb.n[5] = 4096;
    cb.src[6] = bf2;   cb.dst[6] = bf2_c;         cb.n[6] = 1024;
    cb.src[7] = g1;    cb.dst[7] = g1_c;          cb.n[7] = 1024;
    cb.src[8] = be1;   cb.dst[8] = be1_c;         cb.n[8] = 1024;
    cb.src[9] = g2;    cb.dst[9] = g2_c;          cb.n[9] = 1024;
    cb.src[10] = be2;  cb.dst[10] = be2_c;        cb.n[10] = 1024;
    cvt_small_k<<<dim3(11), blk, 0, stream>>>(cb, flag);
    // 1. attention weight transposes
    transpose_k<<<dim3(16, 16, 1), blk, 0, stream>>>(Wq, WqkvT, 1024, 1024, flag);
    transpose_k<<<dim3(16, 16, 1), blk, 0, stream>>>(Wk, WqkvT + 1024 * 1024, 1024, 1024, flag);
    transpose_k<<<dim3(16, 16, 1), blk, 0, stream>>>(Wv, WqkvT + 2048 * 1024, 1024, 1024, flag);
    transpose_k<<<dim3(16, 16, 1), blk, 0, stream>>>(Wo, WoT, 1024, 1024, flag);
    // 2. fused QKV projection (N=3072, epilogue splits into Qb/Kb/Vb); 384 wgs
    gemm256<<<dim3(384), blk5, 0, stream>>>(xc, 1024, WqkvT, 1024, bqkv_c, Qb, 1024, 8192, 3072, 1024, FLAG_QKV, nullptr, nullptr);
    // 3. V -> Vt[b, d, s]
    transpose_k<<<dim3(16, 16, 8), blk, 0, stream>>>(Vb, Vtb, 1024, 1024, nullptr);
    // 4. attention -> ctx (1024 linear blocks, XCD-locality remap)
    attn_k<<<dim3(1024), blk, 0, stream>>>(Qb, Kb, Vtb, mask_c, ctxb);
    // 5+6. y = ctx @ Wo + bo ; x1 = LN(x + y)
    if (do_split) {
        // split-K x2: 256 wgs, partials fp32 (yw0 over dead Q/K, pk1 at 89 MB)
        gemm256<<<dim3(256), blk5, 0, stream>>>(ctxb, 1024, WoT, 1024, bo_c, yw0, 1024, 8192, 1024, 1024, FLAG_SPLITK, nullptr, pk1);
        ln_add2f<<<dim3(8192), blk, 0, stream>>>(xc, yw0, pk1, g1_c, be1_c, x1b);
    } else {
        gemm256<<<dim3(128), blk5, 0, stream>>>(ctxb, 1024, WoT, 1024, bo_c, yb, 1024, 8192, 1024, 1024, 0, nullptr, nullptr);
        ln_add<<<dim3(8192), blk, 0, stream>>>(xc, yb, g1_c, be1_c, x1b);
    }
    // 6.5 W1T into 0-8 MB (QKV/Wo weights dead)
    transpose_k<<<dim3(64, 16, 1), blk, 0, stream>>>(W1, W1T, 1024, 4096, flag);
    // 7. h = relu(x1 @ W1 + bf1), N=4096, hb = 24-88 MB; 512 wgs (2 rounds)
    gemm256<<<dim3(512), blk5, 0, stream>>>(x1b, 1024, W1T, 1024, bf1_c, hb, 4096, 8192, 4096, 1024, FLAG_RELU, nullptr, nullptr);
    // 7.5 W2T into 0-8 MB (W1T dead)
    transpose_k<<<dim3(16, 64, 1), blk, 0, stream>>>(W2, W2T, 4096, 1024, flag);
    // 8+9. y2 = h @ W2 + bf2 ; out = LN(x1 + y2)
    if (do_split) {
        gemm256<<<dim3(256), blk5, 0, stream>>>(hb, 4096, W2T, 4096, bf2_c, p0f, 1024, 8192, 1024, 4096, FLAG_SPLITK, nullptr, pk1);
        ln_add_out2f<<<dim3(8192), blk, 0, stream>>>(x1b, p0f, pk1, g2_c, be2_c, d_out, flag);
    } else {
        gemm256<<<dim3(128), blk5, 0, stream>>>(hb, 4096, W2T, 4096, bf2_c, d_out, 1024, 8192, 1024, 4096, FLAG_OUTF32, flag, nullptr);
        ln_add_out<<<dim3(8192), blk, 0, stream>>>(x1b, d_out, g2_c, be2_c, d_out, flag);
    }
}